// Round 17
// baseline (448.744 us; speedup 1.0000x reference)
//
#include <hip/hip_runtime.h>
#include <hip/hip_bf16.h>
#include <cmath>

using bf16 = __hip_bfloat16;
using bf16x8 = __attribute__((ext_vector_type(8))) short;
using bf16x4 = __attribute__((ext_vector_type(4))) short;
using f32x4v = __attribute__((ext_vector_type(4))) float;

static constexpr int BB  = 8;
static constexpr int HW  = 64;
static constexpr int NN  = HW * HW;     // 4096
static constexpr int CC  = 256;
static constexpr int CIN = 64;
static constexpr int DH  = 1024;
static constexpr int MM  = BB * NN;     // 32768

__device__ __forceinline__ bf16 f2b(float v) { return __float2bfloat16(v); }
__device__ __forceinline__ float b2f(bf16 v) { return __bfloat162float(v); }
__device__ __forceinline__ float tf(float v) { return v; }
__device__ __forceinline__ float tf(bf16 v)  { return b2f(v); }
__device__ __forceinline__ float frcp(float x) { return __builtin_amdgcn_rcpf(x); }
__device__ __forceinline__ float sigmf(float x) { return frcp(1.f + __expf(-x)); }
__device__ __forceinline__ float siluf(float x) { return x * sigmf(x); }
__device__ __forceinline__ float geluf(float x) {
  float z = x * fmaf(x * x, 0.07135481627f, 1.5957691216f);
  return x * sigmf(z);
}
__device__ __forceinline__ float tanhfast(float x) {
  return 1.f - 2.f * frcp(1.f + __expf(2.f * x));
}

// async global->LDS, 16B per lane; LDS dest must be linear in lane id.
__device__ __forceinline__ void stage16(const bf16* g, bf16* l) {
  __builtin_amdgcn_global_load_lds(
      (const __attribute__((address_space(1))) void*)g,
      (__attribute__((address_space(3))) void*)l, 16, 0, 0);
}

// ---------- pos table [N][C] ----------
__global__ __launch_bounds__(256) void pos_kern(float* __restrict__ pos) {
  int n = blockIdx.x, o = threadIdx.x;
  int yy = n >> 6, xx = n & 63;
  int i = o & 63, q = o >> 6;
  float omega = __expf((float)i * -0.14391156831212787f);  // 10000^(-i/64)
  float coord = (q < 2) ? (float)xx : (float)yy;
  float ang = coord * omega;
  pos[(size_t)n * CC + o] = (q & 1) ? __cosf(ang) : __sinf(ang);
}

// ---------- pre-convert weights to bf16 ----------
__global__ __launch_bounds__(256) void cvt_weights(
    const float* __restrict__ wq, const float* __restrict__ wk,
    const float* __restrict__ wv, const float* __restrict__ wo,
    const float* __restrict__ we, const float* __restrict__ wp,
    const float* __restrict__ qb, const float* __restrict__ kb,
    const float* __restrict__ vb,
    bf16* __restrict__ wqkvb, bf16* __restrict__ wob,
    bf16* __restrict__ web, bf16* __restrict__ wpb,
    float* __restrict__ bqkv, float* __restrict__ ksum) {
  int i = blockIdx.x * 256 + threadIdx.x;
  switch (blockIdx.y) {
    case 0: if (i < 65536) wqkvb[i] = f2b(wq[i]);
            if (i < 2048) ksum[i] = 0.f;
            break;
    case 1: if (i < 65536) wqkvb[65536 + i] = f2b(wk[i]);
            if (i < 768) bqkv[i] = (i < 256) ? qb[i] : (i < 512) ? kb[i - 256] : vb[i - 512];
            break;
    case 2: if (i < 65536) wqkvb[131072 + i] = f2b(wv[i]); break;
    case 3: if (i < 65536) wob[i] = f2b(wo[i]); break;
    case 4: web[i] = f2b(we[i]); break;  // 262144
    case 5: wpb[i] = f2b(wp[i]); break;  // 262144
  }
}

// ---------- in_proj: NCHW(64ch) -> [B*N,256] f32 + bf16, + SiLU ----------
__global__ __launch_bounds__(256) void inproj_tile(const float* __restrict__ X,
                                                   const float* __restrict__ W,
                                                   float* __restrict__ H,
                                                   bf16* __restrict__ Hb) {
  __shared__ float Xs[16][68];
  __shared__ float Ws[16][68];
  int m0 = blockIdx.x * 64, o0 = blockIdx.y * 64, b = blockIdx.z;
  int tid = threadIdx.x, tx = tid & 15, ty = tid >> 4;
  float acc[4][4] = {};
  for (int k0 = 0; k0 < CIN; k0 += 16) {
    {
      int mm = tid & 63, kk0 = tid >> 6;
#pragma unroll
      for (int i = 0; i < 4; ++i) {
        int kk = kk0 * 4 + i;
        Xs[kk][mm] = X[((size_t)(b * CIN + k0 + kk)) * NN + m0 + mm];
      }
    }
    {
      int kk = tid & 15, oo0 = tid >> 4;
#pragma unroll
      for (int i = 0; i < 4; ++i) {
        int oo = oo0 + i * 16;
        Ws[kk][oo] = W[(size_t)(o0 + oo) * CIN + k0 + kk];
      }
    }
    __syncthreads();
#pragma unroll
    for (int kk = 0; kk < 16; ++kk) {
      float xv[4], wv[4];
#pragma unroll
      for (int a = 0; a < 4; ++a) xv[a] = Xs[kk][ty * 4 + a];
#pragma unroll
      for (int c = 0; c < 4; ++c) wv[c] = Ws[kk][tx * 4 + c];
#pragma unroll
      for (int a = 0; a < 4; ++a)
#pragma unroll
        for (int c = 0; c < 4; ++c) acc[a][c] += xv[a] * wv[c];
    }
    __syncthreads();
  }
#pragma unroll
  for (int a = 0; a < 4; ++a) {
    int m = m0 + ty * 4 + a;
#pragma unroll
    for (int c = 0; c < 4; ++c) {
      int o = o0 + tx * 4 + c;
      float v = siluf(acc[a][c]);
      size_t idx = ((size_t)b * NN + m) * CC + o;
      H[idx] = v;
      Hb[idx] = f2b(v);
    }
  }
}

// ---------- f32 tiled GEMM (out_proj, with fused mona2 gate on input) ----------
__global__ __launch_bounds__(256) void outproj_tile(const float* __restrict__ T2,
                                                    const float* __restrict__ gate,
                                                    const float* __restrict__ W,
                                                    float* __restrict__ Y) {
  __shared__ float Xs[16][68];
  __shared__ float Ws[16][68];
  int n0 = blockIdx.x * 64, b = blockIdx.z;
  size_t mbase = (size_t)b * NN;
  const float* gb = gate + b * CC;
  int tid = threadIdx.x, tx = tid & 15, ty = tid >> 4;
  float acc[4][4] = {};
  for (int k0 = 0; k0 < CC; k0 += 16) {
    int kk = tid & 15, rr0 = tid >> 4;
    float gk = gb[k0 + kk];
#pragma unroll
    for (int i = 0; i < 4; ++i) {
      int rr = rr0 + i * 16;
      Xs[kk][rr] = T2[(mbase + n0 + rr) * CC + k0 + kk] * gk;  // fused Y = T2*gate
      Ws[kk][rr] = (rr < CIN) ? W[(size_t)rr * CC + k0 + kk] : 0.f;
    }
    __syncthreads();
#pragma unroll
    for (int kk2 = 0; kk2 < 16; ++kk2) {
      float xv[4], wv[4];
#pragma unroll
      for (int a = 0; a < 4; ++a) xv[a] = Xs[kk2][ty * 4 + a];
#pragma unroll
      for (int c = 0; c < 4; ++c) wv[c] = Ws[kk2][tx * 4 + c];
#pragma unroll
      for (int a = 0; a < 4; ++a)
#pragma unroll
        for (int c = 0; c < 4; ++c) acc[a][c] += xv[a] * wv[c];
    }
    __syncthreads();
  }
#pragma unroll
  for (int a = 0; a < 4; ++a) {
    int n = n0 + ty * 4 + a;
#pragma unroll
    for (int c = 0; c < 4; ++c) {
      int o = tx * 4 + c;
      if (o < CIN)
        Y[(size_t)(b * CIN + o) * NN + n] = siluf(acc[a][c]);
    }
  }
}

// ---------- pure-bf16 MFMA GEMM core, global_load_lds staging, fused epilogues ----------
enum { EPI_PLAIN = 0, EPI_BIAS = 1, EPI_NUM = 3, EPI_RESID = 4, EPI_ADD1 = 5 };

__device__ __forceinline__ void storeO(float* p, float v) { *p = v; }
__device__ __forceinline__ void storeO(bf16* p, float v) { *p = f2b(v); }

// KVS: per-batch split-16 kv mode (z = b*16+ks)
// XSWZ: bijective XCD-chunked swizzle — blocks sharing an A m-tile co-locate on one XCD.
// BM64: 64xO128 tile, 4 waves x (64m x 32o) — doubles grid for occupancy-limited GEMMs.
// EPI_RESID: v + 2*(aux2[m][o] * aux1[(m>>12)*CC+o])   (T1 * gate1, fused mona1 scale)
template <int EPI, bool WPB, bool KVS, bool XSWZ, bool BM64, typename YT, typename A2T>
__global__ __launch_bounds__(256) void gemm_bf16(const bf16* __restrict__ X,
                                                 const bf16* __restrict__ W,
                                                 const float* __restrict__ bias,
                                                 YT* __restrict__ Y, int Kd, int Od,
                                                 const float* __restrict__ aux1,   // rden | gate1
                                                 const A2T* __restrict__ aux2) {   // H | T1
  constexpr int BM  = BM64 ? 64 : 128;
  constexpr int NNT = BM64 ? 2 : 4;
  __shared__ __align__(16) bf16 As[BM * 32];
  __shared__ __align__(16) bf16 Bs[128 * 32];
  int m0, o0;
  if (XSWZ) {
    int gy = gridDim.y;
    int nwg = gridDim.x * gy;
    int lin = blockIdx.y * gridDim.x + blockIdx.x;
    int q = nwg >> 3;
    int lin2 = (lin & 7) * q + (lin >> 3);
    m0 = (lin2 / gy) * BM;
    o0 = (lin2 % gy) * 128;
  } else {
    m0 = blockIdx.x * BM;
    o0 = blockIdx.y * 128;
  }
  int kbeg = 0, kend = Kd;
  if (KVS) {
    int b = blockIdx.z >> 4, ks = blockIdx.z & 15;
    size_t off = (size_t)b * CC * Kd;
    X += off; W += off;
    Y += (size_t)blockIdx.z * CC * CC;
    kbeg = ks * (Kd / 16); kend = kbeg + Kd / 16;
  }
  const bf16* Wp = WPB ? (W + (size_t)(m0 >> 12) * Kd * Od) : W;
  int t = threadIdx.x;
  int l = t & 63, w = t >> 6;
  int wm = BM64 ? 0 : (w >> 1) * 64;
  int wn = BM64 ? w * 32 : (w & 1) * 64;
  int lr = l & 15, lq = l >> 4;
  int srow = t >> 2, skc = (t & 3) * 8;
  f32x4v acc[4][NNT] = {};
  for (int k0 = kbeg; k0 < kend; k0 += 32) {
    stage16(X + (size_t)(m0 + srow) * Kd + k0 + skc, As + t * 8);
    if (!BM64)
      stage16(X + (size_t)(m0 + 64 + srow) * Kd + k0 + skc, As + 2048 + t * 8);
    stage16(Wp + (size_t)(o0 + srow) * Kd + k0 + skc, Bs + t * 8);
    stage16(Wp + (size_t)(o0 + 64 + srow) * Kd + k0 + skc, Bs + 2048 + t * 8);
    __syncthreads();
    bf16x8 af[4], bfr[NNT];
#pragma unroll
    for (int mt = 0; mt < 4; ++mt)
      af[mt] = *(const bf16x8*)(As + (wm + mt * 16 + lr) * 32 + lq * 8);
#pragma unroll
    for (int nt = 0; nt < NNT; ++nt)
      bfr[nt] = *(const bf16x8*)(Bs + (wn + nt * 16 + lr) * 32 + lq * 8);
#pragma unroll
    for (int mt = 0; mt < 4; ++mt)
#pragma unroll
      for (int nt = 0; nt < NNT; ++nt)
        acc[mt][nt] = __builtin_amdgcn_mfma_f32_16x16x32_bf16(af[mt], bfr[nt], acc[mt][nt], 0, 0, 0);
    __syncthreads();
  }
  // C/D: col = lane&15 (o), row = (lane>>4)*4 + reg (m)
#pragma unroll
  for (int nt = 0; nt < NNT; ++nt) {
    int o = o0 + wn + nt * 16 + lr;
    float bv = (EPI == EPI_PLAIN || EPI == EPI_NUM) ? 0.f : bias[o];
#pragma unroll
    for (int mt = 0; mt < 4; ++mt) {
      int mb = m0 + wm + mt * 16 + lq * 4;
#pragma unroll
      for (int r = 0; r < 4; ++r) {
        int m = mb + r;
        float v = acc[mt][nt][r] + bv;
        if constexpr (EPI == EPI_PLAIN || EPI == EPI_BIAS) {
          storeO(Y + (size_t)m * Od + o, v);
        } else if constexpr (EPI == EPI_NUM) {
          storeO(Y + (size_t)m * Od + o, v * aux1[m]);
        } else if constexpr (EPI == EPI_ADD1) {
          storeO(Y + (size_t)m * Od + o, v + tf(aux2[(size_t)m * Od + o]));
        } else {  // EPI_RESID: v + 2*(T1*gate1)  (bit-identical to old stored-H path)
          int gb = m >> 12;
          float u1 = tf(aux2[(size_t)m * Od + o]) * aux1[gb * CC + o];
          storeO(Y + (size_t)m * Od + o, v + 2.f * u1);
        }
      }
    }
  }
}

// ---------- QKV post-math: Q -> phiQ [m][c]; K -> KT [b][c][n] + ksum; V -> VT ----------
__global__ __launch_bounds__(256) void qkmath_kern(const bf16* __restrict__ QKV,  // [MM][768]
                                                   const float* __restrict__ pose,
                                                   const bf16* __restrict__ psi,
                                                   bf16* __restrict__ PQ,
                                                   bf16* __restrict__ KT,
                                                   bf16* __restrict__ VTo,
                                                   float* __restrict__ ksum) {
  __shared__ bf16 Ts[64][258];   // row stride 516B = 129 dwords (odd): conflict-free col reads
  int sec = blockIdx.y;
  int m0 = blockIdx.x * 64;
  int b = m0 >> 12, n0 = m0 & (NN - 1);
  int t = threadIdx.x;
  int cg = (t & 31) * 8;   // col group
  int rg = t >> 5;         // row sub-index
  if (sec == 0) {
#pragma unroll
    for (int p = 0; p < 8; ++p) {
      int r = p * 8 + rg;
      size_t m = (size_t)m0 + r;
      int n = (int)(m & (NN - 1));
      union { bf16x8 v; bf16 e[8]; } qv, pv, ov;
      qv.v = *(const bf16x8*)(QKV + m * 768 + cg);
      pv.v = *(const bf16x8*)(psi + m * CC + cg);
      const float* pr = pose + (size_t)n * CC + cg;
      f32x4v p0 = *(const f32x4v*)pr;
      f32x4v p1 = *(const f32x4v*)(pr + 4);
#pragma unroll
      for (int j = 0; j < 8; ++j) {
        float pj = (j < 4) ? p0[j] : p1[j - 4];
        float v = (b2f(qv.e[j]) + pj) * b2f(pv.e[j]);
        v = fmaxf(v, 0.f);
        ov.e[j] = f2b(v * v);
      }
      *(bf16x8*)(PQ + m * CC + cg) = ov.v;
    }
    return;
  }
  const bool KM = (sec == 1);
#pragma unroll
  for (int p = 0; p < 8; ++p) {
    int r = p * 8 + rg;
    size_t m = (size_t)m0 + r;
    union { bf16x8 v; bf16 e[8]; } qv, ov;
    qv.v = *(const bf16x8*)(QKV + m * 768 + sec * 256 + cg);
    if (KM) {
      int n = (int)(m & (NN - 1));
      union { bf16x8 v; bf16 e[8]; } pv;
      pv.v = *(const bf16x8*)(psi + m * CC + cg);
      const float* pr = pose + (size_t)n * CC + cg;
      f32x4v p0 = *(const f32x4v*)pr;
      f32x4v p1 = *(const f32x4v*)(pr + 4);
#pragma unroll
      for (int j = 0; j < 8; ++j) {
        float pj = (j < 4) ? p0[j] : p1[j - 4];
        float v = (b2f(qv.e[j]) + pj) * b2f(pv.e[j]);
        v = fmaxf(v, 0.f);
        ov.e[j] = f2b(v * v);
      }
    } else {
      ov.v = qv.v;   // V: pass bf16 bits through unchanged
    }
    *(bf16x8*)(&Ts[r][cg]) = ov.v;
  }
  __syncthreads();
  int wv = t >> 6, lane = t & 63;
  bf16* base = KM ? KT : VTo;
  int nloc = (lane & 7) * 8;
  int gsub = lane >> 3;
#pragma unroll
  for (int k = 0; k < 8; ++k) {
    int c = wv * 64 + k * 8 + gsub;
    union { bf16x8 v; bf16 e[8]; } pk;
#pragma unroll
    for (int i = 0; i < 8; ++i) pk.e[i] = Ts[nloc + i][c];
    *(bf16x8*)(base + ((size_t)(b * CC + c)) * NN + n0 + nloc) = pk.v;
    if (KM) {
      float s = 0.f;
#pragma unroll
      for (int i = 0; i < 8; ++i) s += b2f(pk.e[i]);
      s += __shfl_xor(s, 1);
      s += __shfl_xor(s, 2);
      s += __shfl_xor(s, 4);
      if ((lane & 7) == 0) atomicAdd(&ksum[b * CC + c], s);
    }
  }
}

// ---------- kvTb[b][d][c] = bf16(sum_ks kvpartB[b*16+ks][d][c]) (bf16 partials) ----------
__global__ __launch_bounds__(256) void kvred_kern(const bf16* __restrict__ part,
                                                  bf16* __restrict__ kvTb) {
  int d = blockIdx.x, b = blockIdx.y, c = threadIdx.x;
  float s = 0.f;
#pragma unroll
  for (int ks = 0; ks < 16; ++ks)
    s += b2f(part[((size_t)(b * 16 + ks) * CC + d) * CC + c]);
  kvTb[((size_t)b * CC + d) * CC + c] = f2b(s);
}

// ---------- rden: 1 row per wave, 4 rows per block ----------
__global__ __launch_bounds__(256) void den_kern(const bf16* __restrict__ PQ,
                                                const float* __restrict__ ksum,
                                                float* __restrict__ rden) {
  int b = blockIdx.y;
  int n = blockIdx.x * 4 + (threadIdx.x >> 6);
  int lane = threadIdx.x & 63;
  size_t m = (size_t)b * NN + n;
  union { bf16x4 v; bf16 e[4]; } u;
  u.v = *(const bf16x4*)(PQ + m * CC + lane * 4);
  const float* ks = ksum + b * CC + lane * 4;
  float s = 0.f;
#pragma unroll
  for (int j = 0; j < 4; ++j) s += b2f(u.e[j]) * ks[j];
#pragma unroll
  for (int off = 32; off >= 1; off >>= 1) s += __shfl_down(s, off);
  if (lane == 0) rden[m] = 1.f / (s + 1e-5f);
}

// ---------- DyT + fused per-block pool partial ----------
template <bool RESID>
__global__ __launch_bounds__(256) void dyt_kern(const float* __restrict__ X,
                                                const float* __restrict__ R,
                                                const float* __restrict__ g,
                                                const float* __restrict__ bt,
                                                float* __restrict__ T,
                                                float* __restrict__ poolq) {
  int wv = threadIdx.x >> 6;
  int m = blockIdx.x * 4 + wv;
  int lane = threadIdx.x & 63;
  size_t base = (size_t)m * CC + lane * 4;
  f32x4v x = *(const f32x4v*)(X + base);
  if constexpr (RESID) {
    f32x4v r = *(const f32x4v*)(R + base);
#pragma unroll
    for (int j = 0; j < 4; ++j) x[j] += r[j];
  }
  float s = (x[0] + x[1]) + (x[2] + x[3]);
  float q = fmaf(x[0], x[0], fmaf(x[1], x[1], fmaf(x[2], x[2], x[3] * x[3])));
#pragma unroll
  for (int off = 32; off >= 1; off >>= 1) {
    s += __shfl_xor(s, off);
    q += __shfl_xor(q, off);
  }
  float mu = s * (1.f / 256.f);
  float var = (q - 256.f * mu * mu) * (1.f / 255.f);
  float sd = sqrtf(fmaxf(var, 0.f)) + 1e-5f;
  float rs = frcp(sd);
  f32x4v gv = *(const f32x4v*)(g + lane * 4);
  f32x4v bv = *(const f32x4v*)(bt + lane * 4);
  f32x4v o;
#pragma unroll
  for (int j = 0; j < 4; ++j)
    o[j] = tanhfast(fmaf(gv[j] * (x[j] - mu), rs, bv[j]));
  *(f32x4v*)(T + base) = o;
  __shared__ float ps[4][260];
#pragma unroll
  for (int j = 0; j < 4; ++j) ps[wv][lane * 4 + j] = o[j];
  __syncthreads();
  if (wv == 0) {
    f32x4v pv;
#pragma unroll
    for (int j = 0; j < 4; ++j) {
      int c = lane * 4 + j;
      pv[j] = (ps[0][c] + ps[1][c]) + (ps[2][c] + ps[3][c]);
    }
    *(f32x4v*)(poolq + (size_t)blockIdx.x * 256 + lane * 4) = pv;
  }
}

// ---------- poolred: pool16[(b*16+s)][c] = sum of 64 block-partials ----------
__global__ __launch_bounds__(256) void poolred_kern(const float* __restrict__ poolq,
                                                    float* __restrict__ pool16) {
  int s = blockIdx.x, b = blockIdx.y, c = threadIdx.x;
  float acc = 0.f;
#pragma unroll 8
  for (int k = 0; k < 64; ++k)
    acc += poolq[((size_t)(b * 1024 + s * 64 + k)) * 256 + c];
  pool16[(size_t)(b * 16 + s) * 256 + c] = acc;
}

// ---------- gate[b][o] = sigmoid(m_w . pool[b]/4096 + m_b) ----------
__global__ __launch_bounds__(256) void gate_kern(const float* __restrict__ pool16,
                                                 const float* __restrict__ w,
                                                 const float* __restrict__ bias,
                                                 float* __restrict__ gate) {
  int b = blockIdx.x, o = threadIdx.x;
  __shared__ float p[CC];
  float s = 0.f;
#pragma unroll
  for (int k = 0; k < 16; ++k) s += pool16[(size_t)(b * 16 + k) * 256 + o];
  p[o] = s * (1.f / 4096.f);
  __syncthreads();
  float acc = bias[o];
  for (int c = 0; c < CC; ++c) acc += p[c] * w[o * CC + c];
  gate[b * CC + o] = sigmf(acc);
}

// ---------- U1b = bf16(T1 * gate1) ----------
__global__ __launch_bounds__(256) void scale_b16(const float* __restrict__ T,
                                                 const float* __restrict__ gate,
                                                 bf16* __restrict__ Ob) {
  size_t i4 = ((size_t)blockIdx.x * 256 + threadIdx.x) * 4;
  int b = (int)(i4 >> 20);
  int c = (int)(i4 & (CC - 1));
  f32x4v t = *(const f32x4v*)(T + i4);
  f32x4v gv = *(const f32x4v*)(gate + b * CC + c);
  union { bf16x4 v; bf16 e[4]; } ob;
#pragma unroll
  for (int j = 0; j < 4; ++j) ob.e[j] = f2b(t[j] * gv[j]);
  *(bf16x4*)(Ob + i4) = ob.v;
}

// ---------- depthwise 3x3 sliding-window helper (bf16 input, stride templated) ----------
template <int STRIDE>
__device__ __forceinline__ void dw_loadrow_b16(float (&row)[3][4], const bf16* __restrict__ Xb,
                                               int yy, int x, int dl, int dr) {
  if (yy < 0 || yy >= HW) {
#pragma unroll
    for (int cx = 0; cx < 3; ++cx)
#pragma unroll
      for (int j = 0; j < 4; ++j) row[cx][j] = 0.f;
    return;
  }
  const bf16* base = Xb + ((size_t)yy * HW + x) * (size_t)STRIDE;
  union U { bf16x4 v; bf16 e[4]; } um, ul, ur;
  um.v = *(const bf16x4*)base;
  ul.v = *(const bf16x4*)(base + dl);
  ur.v = *(const bf16x4*)(base + dr);
#pragma unroll
  for (int j = 0; j < 4; ++j) {
    row[0][j] = b2f(ul.e[j]);
    row[1][j] = b2f(um.e[j]);
    row[2][j] = b2f(ur.e[j]);
  }
}

// ---------- depthwise 3x3 + sigmoid, bf16 in (Hb) -> bf16 out (psi), 2-row load-ahead ----------
__global__ __launch_bounds__(256) void dwconv_psi_v2(const bf16* __restrict__ X,
                                                     const float* __restrict__ w,
                                                     const float* __restrict__ bias,
                                                     bf16* __restrict__ Y) {
  int i = blockIdx.x;
  int lin = (i & 7) * 64 + (i >> 3);
  int xg = lin & 15, yc = (lin >> 4) & 3, b = lin >> 6;
  int c0 = (threadIdx.x & 63) * 4;
  int x  = xg * 4 + (threadIdx.x >> 6);
  int y0 = yc * 16;
  const bf16* Xb = X + (size_t)b * NN * CC + c0;
  bf16* Yb      = Y + (size_t)b * NN * CC + c0;
  float wt[9][4], bs[4];
#pragma unroll
  for (int j = 0; j < 4; ++j) {
    bs[j] = bias[c0 + j];
#pragma unroll
    for (int t9 = 0; t9 < 9; ++t9) wt[t9][j] = w[(c0 + j) * 9 + t9];
  }
  const bool xl = (x > 0), xr = (x < HW - 1);
  if (!xl) {
#pragma unroll
    for (int j = 0; j < 4; ++j) wt[0][j] = wt[3][j] = wt[6][j] = 0.f;
  }
  if (!xr) {
#pragma unroll
    for (int j = 0; j < 4; ++j) wt[2][j] = wt[5][j] = wt[8][j] = 0.f;
  }
  const int dl = xl ? -CC : 0, dr = xr ? CC : 0;
  float win[5][3][4];
  dw_loadrow_b16<CC>(win[0], Xb, y0 - 1, x, dl, dr);
  dw_loadrow_b16<CC>(win[1], Xb, y0,     x, dl, dr);
  dw_loadrow_b16<CC>(win[2], Xb, y0 + 1, x, dl, dr);
  dw_loadrow_b16<CC>(win[3], Xb, y0 + 2, x, dl, dr);
#pragma unroll
  for (int ii = 0; ii < 16; ++ii) {
    dw_loadrow_b16<CC>(win[(ii + 4) % 5], Xb, y0 + ii + 3, x, dl, dr);
    const int rt = ii % 5, rm = (ii + 1) % 5, rb = (ii + 2) % 5;
    union { bf16x4 v; bf16 e[4]; } o;
#pragma unroll
    for (int j = 0; j < 4; ++j) {
      float a = bs[j];
#pragma unroll
      for (int cx = 0; cx < 3; ++cx) {
        a = fmaf(win[rt][cx][j], wt[cx][j], a);
        a = fmaf(win[rm][cx][j], wt[3 + cx][j], a);
        a = fmaf(win[rb][cx][j], wt[6 + cx][j], a);
      }
      o.e[j] = f2b(sigmf(a));
    }
    *(bf16x4*)(Yb + ((size_t)(y0 + ii) * HW + x) * (size_t)CC) = o.v;
  }
}

// ---------- depthwise 3x3 + gelu, bf16 in/out (1024ch), 2-row load-ahead ----------
__global__ __launch_bounds__(256) void dwconv1024_v2(const bf16* __restrict__ X,
                                                     const float* __restrict__ w,
                                                     const float* __restrict__ bias,
                                                     bf16* __restrict__ Y) {
  int i = blockIdx.x;
  int lin = (i & 7) * 256 + (i >> 3);
  int x = lin & 63, yc = (lin >> 6) & 3, b = lin >> 8;
  int c0 = threadIdx.x * 4;
  int y0 = yc * 16;
  const bf16* Xb = X + (size_t)b * NN * DH + c0;
  bf16* Yb       = Y + (size_t)b * NN * DH + c0;
  float wt[9][4], bs[4];
#pragma unroll
  for (int j = 0; j < 4; ++j) {
    bs[j] = bias[c0 + j];
#pragma unroll
    for (int t9 = 0; t9 < 9; ++t9) wt[t9][j] = w[(c0 + j) * 9 + t9];
  }
  const bool xl = (x > 0), xr = (x < HW - 1);
  if (!xl) {
#pragma unroll
    for (int j = 0; j < 4; ++j) wt[0][j] = wt[3][j] = wt[6][j] = 0.f;
  }
  if (!xr) {
#pragma unroll
    for (int j = 0; j < 4; ++j) wt[2][j] = wt[5][j] = wt[8][j] = 0.f;
  }
  const int dl = xl ? -DH : 0, dr = xr ? DH : 0;
  float win[5][3][4];
  dw_loadrow_b16<DH>(win[0], Xb, y0 - 1, x, dl, dr);
  dw_loadrow_b16<DH>(win[1], Xb, y0,     x, dl, dr);
  dw_loadrow_b16<DH>(win[2], Xb, y0 + 1, x, dl, dr);
  dw_loadrow_b16<DH>(win[3], Xb, y0 + 2, x, dl, dr);
#pragma unroll
  for (int ii = 0; ii < 16; ++ii) {
    dw_loadrow_b16<DH>(win[(ii + 4) % 5], Xb, y0 + ii + 3, x, dl, dr);
    const int rt = ii % 5, rm = (ii + 1) % 5, rb = (ii + 2) % 5;
    union { bf16x4 v; bf16 e[4]; } o;
#pragma unroll
    for (int j = 0; j < 4; ++j) {
      float a = bs[j];
#pragma unroll
      for (int cx = 0; cx < 3; ++cx) {
        a = fmaf(win[rt][cx][j], wt[cx][j], a);
        a = fmaf(win[rm][cx][j], wt[3 + cx][j], a);
        a = fmaf(win[rb][cx][j], wt[6 + cx][j], a);
      }
      o.e[j] = f2b(geluf(a));
    }
    *(bf16x4*)(Yb + ((size_t)(y0 + ii) * HW + x) * (size_t)DH) = o.v;
  }
}

extern "C" void kernel_launch(void* const* d_in, const int* in_sizes, int n_in,
                              void* d_out, int out_size, void* d_ws, size_t ws_size,
                              hipStream_t stream) {
  (void)in_sizes; (void)n_in; (void)out_size; (void)ws_size;
  const float* x       = (const float*)d_in[0];
  const float* in_proj = (const float*)d_in[1];
  const float* wq_w = (const float*)d_in[2];   const float* wq_b = (const float*)d_in[3];
  const float* wk_w = (const float*)d_in[4];   const float* wk_b = (const float*)d_in[5];
  const float* wv_w = (const float*)d_in[6];   const float* wv_b = (const float*)d_in[7];
  const float* wo_w = (const float*)d_in[8];   const float* wo_b = (const float*)d_in[9];
  const float* psi_w = (const float*)d_in[10]; const float* psi_b = (const float*)d_in[11];
  const float* dyt_g = (const float*)d_in[12]; const float* dyt_b = (const float*)d_in[13];
  const float* m1_w = (const float*)d_in[14];  const float* m1_b = (const float*)d_in[15];
  const float* m2_w = (const float*)d_in[16];  const float* m2_b = (const float*)d_in[17];
  const float* we_w = (const float*)d_in[18];  const float* we_b = (const float*)d_in[19];
  const float* dw_w = (const float*)d_in[20];  const float* dw_b = (const float*)d_in[21];
  const float* wp_w = (const float*)d_in[22];  const float* wp_b = (const float*)d_in[23];
  const float* wout = (const float*)d_in[24];
  float* out = (float*)d_out;

  char* ws = (char*)d_ws;
  const size_t MB = 1u << 20;
  // f32 activations
  float* H     = (float*)(ws);               // 0-32MB : h (dead after wo GEMM)
  float* T1    = (float*)(ws);               // 0-32MB : T1 (written by dyt1, after H dead;
                                             //          survives through EDFFN — no overlap with e1/e2)
  float* A     = (float*)(ws + 32 * MB);     // 32-64  : a+h -> U2
  // attention-phase buffers (dead before EDFFN)
  bf16*  psiB  = (bf16*)(ws + 64 * MB);      // 64-80
  bf16*  numb  = (bf16*)(ws + 80 * MB);      // 80-96
  bf16*  phiQ  = (bf16*)(ws + 96 * MB);      // 96-112
  bf16*  Hb    = (bf16*)(ws + 112 * MB);     // 112-128
  bf16*  phiKT = (bf16*)(ws + 128 * MB);     // 128-144 [B][C][N]
  bf16*  VT    = (bf16*)(ws + 144 * MB);     // 144-160 [B][C][N]
  bf16*  QKVr  = (bf16*)(ws + 160 * MB);     // 160-208 [MM][768] (48MB, dead before kv GEMM)
  bf16*  kvpartB = (bf16*)(ws + 160 * MB);   // 160-176 [128][C][C] bf16 (after qkmath)
  // EDFFN overlays
  bf16*  e1    = (bf16*)(ws + 64 * MB);      // 64-128 (64MB; attention bf16 bufs dead)
  bf16*  e2    = (bf16*)(ws + 128 * MB);     // 128-192 (64MB)
  float* T2    = (float*)(ws + 64 * MB);     // 64-96  (e1 dead after dwconv1024)
  bf16*  U1b   = (bf16*)(ws + 192 * MB);     // 192-208 (QKVr dead by scale_b16)
  // bf16 weights (persistent) 208-210
  bf16* wqkvb = (bf16*)(ws + 208 * MB);      // 384KB [768][256]
  bf16* wob   = wqkvb + 196608;              // 128KB
  bf16* web   = wob + 65536;                 // 512KB [1024][256]
  bf16* wpb   = web + 262144;                // 512KB [256][1024]
  float* bqkv = (float*)(wpb + 262144);      // 3KB
  float* pose = (float*)(ws + 210 * MB);     // 210-214
  char*  small = ws + 214 * MB;
  float* ksum  = (float*)(small);                 // 8KB
  float* rden  = (float*)(small + 64 * 1024);     // 128KB
  float* pool16 = (float*)(small + 192 * 1024);   // 128KB [8][16][256]
  float* gate1 = (float*)(small + 704 * 1024);
  float* gate2 = (float*)(small + 720 * 1024);
  bf16*  kvTb  = (bf16*)(small + 768 * 1024);     // 1MB [8][C][C]
  float* poolq = (float*)(ws + 216 * MB);         // 216-224 [8192][256] block partials

  dim3 blk(256);

  pos_kern<<<dim3(NN), blk, 0, stream>>>(pose);
  cvt_weights<<<dim3(1024, 6), blk, 0, stream>>>(wq_w, wk_w, wv_w, wo_w, we_w, wp_w,
                                                 wq_b, wk_b, wv_b,
                                                 wqkvb, wob, web, wpb, bqkv, ksum);
  inproj_tile<<<dim3(64, 4, BB), blk, 0, stream>>>(x, in_proj, H, Hb);

  // ---- attention ----
  dwconv_psi_v2<<<dim3(512), blk, 0, stream>>>(Hb, psi_w, psi_b, psiB);
  gemm_bf16<EPI_BIAS, false, false, true, false, bf16, float>
      <<<dim3(256, 6), blk, 0, stream>>>(Hb, wqkvb, bqkv, QKVr, CC, 768, nullptr, nullptr);
  qkmath_kern<<<dim3(MM / 64, 3), blk, 0, stream>>>(QKVr, pose, psiB, phiQ, phiKT, VT, ksum);
  gemm_bf16<EPI_PLAIN, false, true, false, false, bf16, float>
      <<<dim3(2, 2, 128), blk, 0, stream>>>(VT, phiKT, nullptr, kvpartB, NN, CC, nullptr, nullptr);
  kvred_kern<<<dim3(CC, BB), blk, 0, stream>>>(kvpartB, kvTb);
  den_kern<<<dim3(1024, BB), blk, 0, stream>>>(phiQ, ksum, rden);
  gemm_bf16<EPI_NUM, true, false, true, true, bf16, float>
      <<<dim3(512, 2), blk, 0, stream>>>(phiQ, kvTb, nullptr, numb, CC, CC, rden, nullptr);
  // wo GEMM with fused h-residual: A = wo_out + bias + H   (last read of H)
  gemm_bf16<EPI_ADD1, false, false, true, true, float, float>
      <<<dim3(512, 2), blk, 0, stream>>>(numb, wob, wo_b, A, CC, CC, nullptr, H);

  // ---- U1 = mona1(dyt(h + a)); T1 overwrites H region (H dead) ----
  dyt_kern<false><<<dim3(MM / 4), blk, 0, stream>>>(A, nullptr, dyt_g, dyt_b, T1, poolq);
  poolred_kern<<<dim3(16, BB), blk, 0, stream>>>(poolq, pool16);
  gate_kern<<<dim3(BB), blk, 0, stream>>>(pool16, m1_w, m1_b, gate1);
  scale_b16<<<dim3(MM / 4), blk, 0, stream>>>(T1, gate1, U1b);   // U1b = bf16(T1*gate1)

  // ---- EDFFN, single pass over all 8 batches; U1 residual fused into wp ----
  gemm_bf16<EPI_BIAS, false, false, true, false, bf16, float>
      <<<dim3(256, 8), blk, 0, stream>>>(U1b, web, we_b, e1, CC, DH, nullptr, nullptr);
  dwconv1024_v2<<<dim3(2048), blk, 0, stream>>>(e1, dw_w, dw_b, e2);
  gemm_bf16<EPI_RESID, false, false, true, true, float, float>
      <<<dim3(512, 2), blk, 0, stream>>>(e2, wpb, wp_b, A, DH, CC, gate1, T1);

  // ---- Y = mona2(dyt(U2)); final scale fused into out_proj ----
  dyt_kern<false><<<dim3(MM / 4), blk, 0, stream>>>(A, nullptr, dyt_g, dyt_b, T2, poolq);
  poolred_kern<<<dim3(16, BB), blk, 0, stream>>>(poolq, pool16);
  gate_kern<<<dim3(BB), blk, 0, stream>>>(pool16, m2_w, m2_b, gate2);

  // ---- out_proj + SiLU, transposed write; Y = T2*gate2 applied during staging ----
  outproj_tile<<<dim3(64, 1, BB), blk, 0, stream>>>(T2, gate2, wout, out);
}

// Round 18
// 445.431 us; speedup vs baseline: 1.0074x; 1.0074x over previous
//
#include <hip/hip_runtime.h>
#include <hip/hip_bf16.h>
#include <cmath>

using bf16 = __hip_bfloat16;
using bf16x8 = __attribute__((ext_vector_type(8))) short;
using bf16x4 = __attribute__((ext_vector_type(4))) short;
using f32x4v = __attribute__((ext_vector_type(4))) float;

static constexpr int BB  = 8;
static constexpr int HW  = 64;
static constexpr int NN  = HW * HW;     // 4096
static constexpr int CC  = 256;
static constexpr int CIN = 64;
static constexpr int DH  = 1024;
static constexpr int MM  = BB * NN;     // 32768

__device__ __forceinline__ bf16 f2b(float v) { return __float2bfloat16(v); }
__device__ __forceinline__ float b2f(bf16 v) { return __bfloat162float(v); }
__device__ __forceinline__ float tf(float v) { return v; }
__device__ __forceinline__ float tf(bf16 v)  { return b2f(v); }
__device__ __forceinline__ float frcp(float x) { return __builtin_amdgcn_rcpf(x); }
__device__ __forceinline__ float sigmf(float x) { return frcp(1.f + __expf(-x)); }
__device__ __forceinline__ float siluf(float x) { return x * sigmf(x); }
__device__ __forceinline__ float geluf(float x) {
  float z = x * fmaf(x * x, 0.07135481627f, 1.5957691216f);
  return x * sigmf(z);
}
__device__ __forceinline__ float tanhfast(float x) {
  return 1.f - 2.f * frcp(1.f + __expf(2.f * x));
}

// async global->LDS, 16B per lane; LDS dest must be linear in lane id.
__device__ __forceinline__ void stage16(const bf16* g, bf16* l) {
  __builtin_amdgcn_global_load_lds(
      (const __attribute__((address_space(1))) void*)g,
      (__attribute__((address_space(3))) void*)l, 16, 0, 0);
}

// ---------- pos table [N][C] ----------
__global__ __launch_bounds__(256) void pos_kern(float* __restrict__ pos) {
  int n = blockIdx.x, o = threadIdx.x;
  int yy = n >> 6, xx = n & 63;
  int i = o & 63, q = o >> 6;
  float omega = __expf((float)i * -0.14391156831212787f);  // 10000^(-i/64)
  float coord = (q < 2) ? (float)xx : (float)yy;
  float ang = coord * omega;
  pos[(size_t)n * CC + o] = (q & 1) ? __cosf(ang) : __sinf(ang);
}

// ---------- pre-convert weights to bf16 ----------
__global__ __launch_bounds__(256) void cvt_weights(
    const float* __restrict__ wq, const float* __restrict__ wk,
    const float* __restrict__ wv, const float* __restrict__ wo,
    const float* __restrict__ we, const float* __restrict__ wp,
    const float* __restrict__ qb, const float* __restrict__ kb,
    const float* __restrict__ vb,
    bf16* __restrict__ wqkvb, bf16* __restrict__ wob,
    bf16* __restrict__ web, bf16* __restrict__ wpb,
    float* __restrict__ bqkv, float* __restrict__ ksum) {
  int i = blockIdx.x * 256 + threadIdx.x;
  switch (blockIdx.y) {
    case 0: if (i < 65536) wqkvb[i] = f2b(wq[i]);
            if (i < 2048) ksum[i] = 0.f;
            break;
    case 1: if (i < 65536) wqkvb[65536 + i] = f2b(wk[i]);
            if (i < 768) bqkv[i] = (i < 256) ? qb[i] : (i < 512) ? kb[i - 256] : vb[i - 512];
            break;
    case 2: if (i < 65536) wqkvb[131072 + i] = f2b(wv[i]); break;
    case 3: if (i < 65536) wob[i] = f2b(wo[i]); break;
    case 4: web[i] = f2b(we[i]); break;  // 262144
    case 5: wpb[i] = f2b(wp[i]); break;  // 262144
  }
}

// ---------- in_proj: NCHW(64ch) -> [B*N,256] f32 + bf16, + SiLU ----------
__global__ __launch_bounds__(256) void inproj_tile(const float* __restrict__ X,
                                                   const float* __restrict__ W,
                                                   float* __restrict__ H,
                                                   bf16* __restrict__ Hb) {
  __shared__ float Xs[16][68];
  __shared__ float Ws[16][68];
  int m0 = blockIdx.x * 64, o0 = blockIdx.y * 64, b = blockIdx.z;
  int tid = threadIdx.x, tx = tid & 15, ty = tid >> 4;
  float acc[4][4] = {};
  for (int k0 = 0; k0 < CIN; k0 += 16) {
    {
      int mm = tid & 63, kk0 = tid >> 6;
#pragma unroll
      for (int i = 0; i < 4; ++i) {
        int kk = kk0 * 4 + i;
        Xs[kk][mm] = X[((size_t)(b * CIN + k0 + kk)) * NN + m0 + mm];
      }
    }
    {
      int kk = tid & 15, oo0 = tid >> 4;
#pragma unroll
      for (int i = 0; i < 4; ++i) {
        int oo = oo0 + i * 16;
        Ws[kk][oo] = W[(size_t)(o0 + oo) * CIN + k0 + kk];
      }
    }
    __syncthreads();
#pragma unroll
    for (int kk = 0; kk < 16; ++kk) {
      float xv[4], wv[4];
#pragma unroll
      for (int a = 0; a < 4; ++a) xv[a] = Xs[kk][ty * 4 + a];
#pragma unroll
      for (int c = 0; c < 4; ++c) wv[c] = Ws[kk][tx * 4 + c];
#pragma unroll
      for (int a = 0; a < 4; ++a)
#pragma unroll
        for (int c = 0; c < 4; ++c) acc[a][c] += xv[a] * wv[c];
    }
    __syncthreads();
  }
#pragma unroll
  for (int a = 0; a < 4; ++a) {
    int m = m0 + ty * 4 + a;
#pragma unroll
    for (int c = 0; c < 4; ++c) {
      int o = o0 + tx * 4 + c;
      float v = siluf(acc[a][c]);
      size_t idx = ((size_t)b * NN + m) * CC + o;
      H[idx] = v;
      Hb[idx] = f2b(v);
    }
  }
}

// ---------- f32 tiled GEMM (out_proj, with fused mona2 gate on input) ----------
__global__ __launch_bounds__(256) void outproj_tile(const float* __restrict__ T2,
                                                    const float* __restrict__ gate,
                                                    const float* __restrict__ W,
                                                    float* __restrict__ Y) {
  __shared__ float Xs[16][68];
  __shared__ float Ws[16][68];
  int n0 = blockIdx.x * 64, b = blockIdx.z;
  size_t mbase = (size_t)b * NN;
  const float* gb = gate + b * CC;
  int tid = threadIdx.x, tx = tid & 15, ty = tid >> 4;
  float acc[4][4] = {};
  for (int k0 = 0; k0 < CC; k0 += 16) {
    int kk = tid & 15, rr0 = tid >> 4;
    float gk = gb[k0 + kk];
#pragma unroll
    for (int i = 0; i < 4; ++i) {
      int rr = rr0 + i * 16;
      Xs[kk][rr] = T2[(mbase + n0 + rr) * CC + k0 + kk] * gk;  // fused Y = T2*gate
      Ws[kk][rr] = (rr < CIN) ? W[(size_t)rr * CC + k0 + kk] : 0.f;
    }
    __syncthreads();
#pragma unroll
    for (int kk2 = 0; kk2 < 16; ++kk2) {
      float xv[4], wv[4];
#pragma unroll
      for (int a = 0; a < 4; ++a) xv[a] = Xs[kk2][ty * 4 + a];
#pragma unroll
      for (int c = 0; c < 4; ++c) wv[c] = Ws[kk2][tx * 4 + c];
#pragma unroll
      for (int a = 0; a < 4; ++a)
#pragma unroll
        for (int c = 0; c < 4; ++c) acc[a][c] += xv[a] * wv[c];
    }
    __syncthreads();
  }
#pragma unroll
  for (int a = 0; a < 4; ++a) {
    int n = n0 + ty * 4 + a;
#pragma unroll
    for (int c = 0; c < 4; ++c) {
      int o = tx * 4 + c;
      if (o < CIN)
        Y[(size_t)(b * CIN + o) * NN + n] = siluf(acc[a][c]);
    }
  }
}

// ---------- pure-bf16 MFMA GEMM core, global_load_lds staging, fused epilogues ----------
enum { EPI_PLAIN = 0, EPI_BIAS = 1, EPI_NUM = 3, EPI_RESID = 4, EPI_ADD1 = 5 };

__device__ __forceinline__ void storeO(float* p, float v) { *p = v; }
__device__ __forceinline__ void storeO(bf16* p, float v) { *p = f2b(v); }

// KVS: per-batch split-16 kv mode (z = b*16+ks)
// XSWZ: bijective XCD-chunked swizzle — blocks sharing an A m-tile co-locate on one XCD.
// EPI_RESID: v + 2*aux2[m][o]  (U1b bf16 residual, one extra bf16 rounding vs T1*gate1)
template <int EPI, bool WPB, bool KVS, bool XSWZ, typename YT, typename A2T>
__global__ __launch_bounds__(256) void gemm_bf16(const bf16* __restrict__ X,
                                                 const bf16* __restrict__ W,
                                                 const float* __restrict__ bias,
                                                 YT* __restrict__ Y, int Kd, int Od,
                                                 const float* __restrict__ aux1,   // rden
                                                 const A2T* __restrict__ aux2) {   // H | U1b
  __shared__ __align__(16) bf16 As[128 * 32];
  __shared__ __align__(16) bf16 Bs[128 * 32];
  int m0, o0;
  if (XSWZ) {
    int gy = gridDim.y;
    int nwg = gridDim.x * gy;
    int lin = blockIdx.y * gridDim.x + blockIdx.x;
    int q = nwg >> 3;
    int lin2 = (lin & 7) * q + (lin >> 3);
    m0 = (lin2 / gy) * 128;
    o0 = (lin2 % gy) * 128;
  } else {
    m0 = blockIdx.x * 128;
    o0 = blockIdx.y * 128;
  }
  int kbeg = 0, kend = Kd;
  if (KVS) {
    int b = blockIdx.z >> 4, ks = blockIdx.z & 15;
    size_t off = (size_t)b * CC * Kd;
    X += off; W += off;
    Y += (size_t)blockIdx.z * CC * CC;
    kbeg = ks * (Kd / 16); kend = kbeg + Kd / 16;
  }
  const bf16* Wp = WPB ? (W + (size_t)(m0 >> 12) * Kd * Od) : W;
  int t = threadIdx.x;
  int l = t & 63, w = t >> 6;
  int wm = (w >> 1) * 64, wn = (w & 1) * 64;
  int lr = l & 15, lq = l >> 4;
  int srow = t >> 2, skc = (t & 3) * 8;
  f32x4v acc[4][4] = {};
  for (int k0 = kbeg; k0 < kend; k0 += 32) {
    stage16(X + (size_t)(m0 + srow) * Kd + k0 + skc, As + t * 8);
    stage16(X + (size_t)(m0 + 64 + srow) * Kd + k0 + skc, As + 2048 + t * 8);
    stage16(Wp + (size_t)(o0 + srow) * Kd + k0 + skc, Bs + t * 8);
    stage16(Wp + (size_t)(o0 + 64 + srow) * Kd + k0 + skc, Bs + 2048 + t * 8);
    __syncthreads();
    bf16x8 af[4], bfr[4];
#pragma unroll
    for (int mt = 0; mt < 4; ++mt)
      af[mt] = *(const bf16x8*)(As + (wm + mt * 16 + lr) * 32 + lq * 8);
#pragma unroll
    for (int nt = 0; nt < 4; ++nt)
      bfr[nt] = *(const bf16x8*)(Bs + (wn + nt * 16 + lr) * 32 + lq * 8);
#pragma unroll
    for (int mt = 0; mt < 4; ++mt)
#pragma unroll
      for (int nt = 0; nt < 4; ++nt)
        acc[mt][nt] = __builtin_amdgcn_mfma_f32_16x16x32_bf16(af[mt], bfr[nt], acc[mt][nt], 0, 0, 0);
    __syncthreads();
  }
  // C/D: col = lane&15 (o), row = (lane>>4)*4 + reg (m)
#pragma unroll
  for (int nt = 0; nt < 4; ++nt) {
    int o = o0 + wn + nt * 16 + lr;
    float bv = (EPI == EPI_PLAIN || EPI == EPI_NUM) ? 0.f : bias[o];
#pragma unroll
    for (int mt = 0; mt < 4; ++mt) {
      int mb = m0 + wm + mt * 16 + lq * 4;
#pragma unroll
      for (int r = 0; r < 4; ++r) {
        int m = mb + r;
        float v = acc[mt][nt][r] + bv;
        if constexpr (EPI == EPI_PLAIN || EPI == EPI_BIAS) {
          storeO(Y + (size_t)m * Od + o, v);
        } else if constexpr (EPI == EPI_NUM) {
          storeO(Y + (size_t)m * Od + o, v * aux1[m]);
        } else if constexpr (EPI == EPI_ADD1) {
          storeO(Y + (size_t)m * Od + o, v + tf(aux2[(size_t)m * Od + o]));
        } else {  // EPI_RESID: v + 2*U1b[m][o]
          storeO(Y + (size_t)m * Od + o, v + 2.f * tf(aux2[(size_t)m * Od + o]));
        }
      }
    }
  }
}

// ---------- QKV post-math: Q -> phiQ [m][c]; K -> KT [b][c][n] + ksum; V -> VT ----------
__global__ __launch_bounds__(256) void qkmath_kern(const bf16* __restrict__ QKV,  // [MM][768]
                                                   const float* __restrict__ pose,
                                                   const bf16* __restrict__ psi,
                                                   bf16* __restrict__ PQ,
                                                   bf16* __restrict__ KT,
                                                   bf16* __restrict__ VTo,
                                                   float* __restrict__ ksum) {
  __shared__ bf16 Ts[64][258];   // row stride 516B = 129 dwords (odd): conflict-free col reads
  int sec = blockIdx.y;
  int m0 = blockIdx.x * 64;
  int b = m0 >> 12, n0 = m0 & (NN - 1);
  int t = threadIdx.x;
  int cg = (t & 31) * 8;   // col group
  int rg = t >> 5;         // row sub-index
  if (sec == 0) {
#pragma unroll
    for (int p = 0; p < 8; ++p) {
      int r = p * 8 + rg;
      size_t m = (size_t)m0 + r;
      int n = (int)(m & (NN - 1));
      union { bf16x8 v; bf16 e[8]; } qv, pv, ov;
      qv.v = *(const bf16x8*)(QKV + m * 768 + cg);
      pv.v = *(const bf16x8*)(psi + m * CC + cg);
      const float* pr = pose + (size_t)n * CC + cg;
      f32x4v p0 = *(const f32x4v*)pr;
      f32x4v p1 = *(const f32x4v*)(pr + 4);
#pragma unroll
      for (int j = 0; j < 8; ++j) {
        float pj = (j < 4) ? p0[j] : p1[j - 4];
        float v = (b2f(qv.e[j]) + pj) * b2f(pv.e[j]);
        v = fmaxf(v, 0.f);
        ov.e[j] = f2b(v * v);
      }
      *(bf16x8*)(PQ + m * CC + cg) = ov.v;
    }
    return;
  }
  const bool KM = (sec == 1);
#pragma unroll
  for (int p = 0; p < 8; ++p) {
    int r = p * 8 + rg;
    size_t m = (size_t)m0 + r;
    union { bf16x8 v; bf16 e[8]; } qv, ov;
    qv.v = *(const bf16x8*)(QKV + m * 768 + sec * 256 + cg);
    if (KM) {
      int n = (int)(m & (NN - 1));
      union { bf16x8 v; bf16 e[8]; } pv;
      pv.v = *(const bf16x8*)(psi + m * CC + cg);
      const float* pr = pose + (size_t)n * CC + cg;
      f32x4v p0 = *(const f32x4v*)pr;
      f32x4v p1 = *(const f32x4v*)(pr + 4);
#pragma unroll
      for (int j = 0; j < 8; ++j) {
        float pj = (j < 4) ? p0[j] : p1[j - 4];
        float v = (b2f(qv.e[j]) + pj) * b2f(pv.e[j]);
        v = fmaxf(v, 0.f);
        ov.e[j] = f2b(v * v);
      }
    } else {
      ov.v = qv.v;   // V: pass bf16 bits through unchanged
    }
    *(bf16x8*)(&Ts[r][cg]) = ov.v;
  }
  __syncthreads();
  int wv = t >> 6, lane = t & 63;
  bf16* base = KM ? KT : VTo;
  int nloc = (lane & 7) * 8;
  int gsub = lane >> 3;
#pragma unroll
  for (int k = 0; k < 8; ++k) {
    int c = wv * 64 + k * 8 + gsub;
    union { bf16x8 v; bf16 e[8]; } pk;
#pragma unroll
    for (int i = 0; i < 8; ++i) pk.e[i] = Ts[nloc + i][c];
    *(bf16x8*)(base + ((size_t)(b * CC + c)) * NN + n0 + nloc) = pk.v;
    if (KM) {
      float s = 0.f;
#pragma unroll
      for (int i = 0; i < 8; ++i) s += b2f(pk.e[i]);
      s += __shfl_xor(s, 1);
      s += __shfl_xor(s, 2);
      s += __shfl_xor(s, 4);
      if ((lane & 7) == 0) atomicAdd(&ksum[b * CC + c], s);
    }
  }
}

// ---------- kvTb[b][d][c] = bf16(sum_ks kvpartB[b*16+ks][d][c]) (bf16 partials) ----------
__global__ __launch_bounds__(256) void kvred_kern(const bf16* __restrict__ part,
                                                  bf16* __restrict__ kvTb) {
  int d = blockIdx.x, b = blockIdx.y, c = threadIdx.x;
  float s = 0.f;
#pragma unroll
  for (int ks = 0; ks < 16; ++ks)
    s += b2f(part[((size_t)(b * 16 + ks) * CC + d) * CC + c]);
  kvTb[((size_t)b * CC + d) * CC + c] = f2b(s);
}

// ---------- rden: 1 row per wave, 4 rows per block ----------
__global__ __launch_bounds__(256) void den_kern(const bf16* __restrict__ PQ,
                                                const float* __restrict__ ksum,
                                                float* __restrict__ rden) {
  int b = blockIdx.y;
  int n = blockIdx.x * 4 + (threadIdx.x >> 6);
  int lane = threadIdx.x & 63;
  size_t m = (size_t)b * NN + n;
  union { bf16x4 v; bf16 e[4]; } u;
  u.v = *(const bf16x4*)(PQ + m * CC + lane * 4);
  const float* ks = ksum + b * CC + lane * 4;
  float s = 0.f;
#pragma unroll
  for (int j = 0; j < 4; ++j) s += b2f(u.e[j]) * ks[j];
#pragma unroll
  for (int off = 32; off >= 1; off >>= 1) s += __shfl_down(s, off);
  if (lane == 0) rden[m] = 1.f / (s + 1e-5f);
}

// ---------- DyT + fused per-block pool partial ----------
template <bool RESID>
__global__ __launch_bounds__(256) void dyt_kern(const float* __restrict__ X,
                                                const float* __restrict__ R,
                                                const float* __restrict__ g,
                                                const float* __restrict__ bt,
                                                float* __restrict__ T,
                                                float* __restrict__ poolq) {
  int wv = threadIdx.x >> 6;
  int m = blockIdx.x * 4 + wv;
  int lane = threadIdx.x & 63;
  size_t base = (size_t)m * CC + lane * 4;
  f32x4v x = *(const f32x4v*)(X + base);
  if constexpr (RESID) {
    f32x4v r = *(const f32x4v*)(R + base);
#pragma unroll
    for (int j = 0; j < 4; ++j) x[j] += r[j];
  }
  float s = (x[0] + x[1]) + (x[2] + x[3]);
  float q = fmaf(x[0], x[0], fmaf(x[1], x[1], fmaf(x[2], x[2], x[3] * x[3])));
#pragma unroll
  for (int off = 32; off >= 1; off >>= 1) {
    s += __shfl_xor(s, off);
    q += __shfl_xor(q, off);
  }
  float mu = s * (1.f / 256.f);
  float var = (q - 256.f * mu * mu) * (1.f / 255.f);
  float sd = sqrtf(fmaxf(var, 0.f)) + 1e-5f;
  float rs = frcp(sd);
  f32x4v gv = *(const f32x4v*)(g + lane * 4);
  f32x4v bv = *(const f32x4v*)(bt + lane * 4);
  f32x4v o;
#pragma unroll
  for (int j = 0; j < 4; ++j)
    o[j] = tanhfast(fmaf(gv[j] * (x[j] - mu), rs, bv[j]));
  *(f32x4v*)(T + base) = o;
  __shared__ float ps[4][260];
#pragma unroll
  for (int j = 0; j < 4; ++j) ps[wv][lane * 4 + j] = o[j];
  __syncthreads();
  if (wv == 0) {
    f32x4v pv;
#pragma unroll
    for (int j = 0; j < 4; ++j) {
      int c = lane * 4 + j;
      pv[j] = (ps[0][c] + ps[1][c]) + (ps[2][c] + ps[3][c]);
    }
    *(f32x4v*)(poolq + (size_t)blockIdx.x * 256 + lane * 4) = pv;
  }
}

// ---------- poolred: pool16[(b*16+s)][c] = sum of 64 block-partials ----------
__global__ __launch_bounds__(256) void poolred_kern(const float* __restrict__ poolq,
                                                    float* __restrict__ pool16) {
  int s = blockIdx.x, b = blockIdx.y, c = threadIdx.x;
  float acc = 0.f;
#pragma unroll 8
  for (int k = 0; k < 64; ++k)
    acc += poolq[((size_t)(b * 1024 + s * 64 + k)) * 256 + c];
  pool16[(size_t)(b * 16 + s) * 256 + c] = acc;
}

// ---------- gate[b][o] = sigmoid(m_w . pool[b]/4096 + m_b) ----------
__global__ __launch_bounds__(256) void gate_kern(const float* __restrict__ pool16,
                                                 const float* __restrict__ w,
                                                 const float* __restrict__ bias,
                                                 float* __restrict__ gate) {
  int b = blockIdx.x, o = threadIdx.x;
  __shared__ float p[CC];
  float s = 0.f;
#pragma unroll
  for (int k = 0; k < 16; ++k) s += pool16[(size_t)(b * 16 + k) * 256 + o];
  p[o] = s * (1.f / 4096.f);
  __syncthreads();
  float acc = bias[o];
  for (int c = 0; c < CC; ++c) acc += p[c] * w[o * CC + c];
  gate[b * CC + o] = sigmf(acc);
}

// ---------- U1b = bf16(T1 * gate1) ----------
__global__ __launch_bounds__(256) void scale_b16(const float* __restrict__ T,
                                                 const float* __restrict__ gate,
                                                 bf16* __restrict__ Ob) {
  size_t i4 = ((size_t)blockIdx.x * 256 + threadIdx.x) * 4;
  int b = (int)(i4 >> 20);
  int c = (int)(i4 & (CC - 1));
  f32x4v t = *(const f32x4v*)(T + i4);
  f32x4v gv = *(const f32x4v*)(gate + b * CC + c);
  union { bf16x4 v; bf16 e[4]; } ob;
#pragma unroll
  for (int j = 0; j < 4; ++j) ob.e[j] = f2b(t[j] * gv[j]);
  *(bf16x4*)(Ob + i4) = ob.v;
}

// ---------- depthwise 3x3 sliding-window helper (bf16 input, stride templated) ----------
template <int STRIDE>
__device__ __forceinline__ void dw_loadrow_b16(float (&row)[3][4], const bf16* __restrict__ Xb,
                                               int yy, int x, int dl, int dr) {
  if (yy < 0 || yy >= HW) {
#pragma unroll
    for (int cx = 0; cx < 3; ++cx)
#pragma unroll
      for (int j = 0; j < 4; ++j) row[cx][j] = 0.f;
    return;
  }
  const bf16* base = Xb + ((size_t)yy * HW + x) * (size_t)STRIDE;
  union U { bf16x4 v; bf16 e[4]; } um, ul, ur;
  um.v = *(const bf16x4*)base;
  ul.v = *(const bf16x4*)(base + dl);
  ur.v = *(const bf16x4*)(base + dr);
#pragma unroll
  for (int j = 0; j < 4; ++j) {
    row[0][j] = b2f(ul.e[j]);
    row[1][j] = b2f(um.e[j]);
    row[2][j] = b2f(ur.e[j]);
  }
}

// ---------- depthwise 3x3 + sigmoid, bf16 in (Hb) -> bf16 out (psi), 2-row load-ahead ----------
__global__ __launch_bounds__(256) void dwconv_psi_v2(const bf16* __restrict__ X,
                                                     const float* __restrict__ w,
                                                     const float* __restrict__ bias,
                                                     bf16* __restrict__ Y) {
  int i = blockIdx.x;
  int lin = (i & 7) * 64 + (i >> 3);
  int xg = lin & 15, yc = (lin >> 4) & 3, b = lin >> 6;
  int c0 = (threadIdx.x & 63) * 4;
  int x  = xg * 4 + (threadIdx.x >> 6);
  int y0 = yc * 16;
  const bf16* Xb = X + (size_t)b * NN * CC + c0;
  bf16* Yb      = Y + (size_t)b * NN * CC + c0;
  float wt[9][4], bs[4];
#pragma unroll
  for (int j = 0; j < 4; ++j) {
    bs[j] = bias[c0 + j];
#pragma unroll
    for (int t9 = 0; t9 < 9; ++t9) wt[t9][j] = w[(c0 + j) * 9 + t9];
  }
  const bool xl = (x > 0), xr = (x < HW - 1);
  if (!xl) {
#pragma unroll
    for (int j = 0; j < 4; ++j) wt[0][j] = wt[3][j] = wt[6][j] = 0.f;
  }
  if (!xr) {
#pragma unroll
    for (int j = 0; j < 4; ++j) wt[2][j] = wt[5][j] = wt[8][j] = 0.f;
  }
  const int dl = xl ? -CC : 0, dr = xr ? CC : 0;
  float win[5][3][4];
  dw_loadrow_b16<CC>(win[0], Xb, y0 - 1, x, dl, dr);
  dw_loadrow_b16<CC>(win[1], Xb, y0,     x, dl, dr);
  dw_loadrow_b16<CC>(win[2], Xb, y0 + 1, x, dl, dr);
  dw_loadrow_b16<CC>(win[3], Xb, y0 + 2, x, dl, dr);
#pragma unroll
  for (int ii = 0; ii < 16; ++ii) {
    dw_loadrow_b16<CC>(win[(ii + 4) % 5], Xb, y0 + ii + 3, x, dl, dr);
    const int rt = ii % 5, rm = (ii + 1) % 5, rb = (ii + 2) % 5;
    union { bf16x4 v; bf16 e[4]; } o;
#pragma unroll
    for (int j = 0; j < 4; ++j) {
      float a = bs[j];
#pragma unroll
      for (int cx = 0; cx < 3; ++cx) {
        a = fmaf(win[rt][cx][j], wt[cx][j], a);
        a = fmaf(win[rm][cx][j], wt[3 + cx][j], a);
        a = fmaf(win[rb][cx][j], wt[6 + cx][j], a);
      }
      o.e[j] = f2b(sigmf(a));
    }
    *(bf16x4*)(Yb + ((size_t)(y0 + ii) * HW + x) * (size_t)CC) = o.v;
  }
}

// ---------- depthwise 3x3 + gelu, bf16 in/out (1024ch), 2-row load-ahead ----------
__global__ __launch_bounds__(256) void dwconv1024_v2(const bf16* __restrict__ X,
                                                     const float* __restrict__ w,
                                                     const float* __restrict__ bias,
                                                     bf16* __restrict__ Y) {
  int i = blockIdx.x;
  int lin = (i & 7) * 256 + (i >> 3);
  int x = lin & 63, yc = (lin >> 6) & 3, b = lin >> 8;
  int c0 = threadIdx.x * 4;
  int y0 = yc * 16;
  const bf16* Xb = X + (size_t)b * NN * DH + c0;
  bf16* Yb       = Y + (size_t)b * NN * DH + c0;
  float wt[9][4], bs[4];
#pragma unroll
  for (int j = 0; j < 4; ++j) {
    bs[j] = bias[c0 + j];
#pragma unroll
    for (int t9 = 0; t9 < 9; ++t9) wt[t9][j] = w[(c0 + j) * 9 + t9];
  }
  const bool xl = (x > 0), xr = (x < HW - 1);
  if (!xl) {
#pragma unroll
    for (int j = 0; j < 4; ++j) wt[0][j] = wt[3][j] = wt[6][j] = 0.f;
  }
  if (!xr) {
#pragma unroll
    for (int j = 0; j < 4; ++j) wt[2][j] = wt[5][j] = wt[8][j] = 0.f;
  }
  const int dl = xl ? -DH : 0, dr = xr ? DH : 0;
  float win[5][3][4];
  dw_loadrow_b16<DH>(win[0], Xb, y0 - 1, x, dl, dr);
  dw_loadrow_b16<DH>(win[1], Xb, y0,     x, dl, dr);
  dw_loadrow_b16<DH>(win[2], Xb, y0 + 1, x, dl, dr);
  dw_loadrow_b16<DH>(win[3], Xb, y0 + 2, x, dl, dr);
#pragma unroll
  for (int ii = 0; ii < 16; ++ii) {
    dw_loadrow_b16<DH>(win[(ii + 4) % 5], Xb, y0 + ii + 3, x, dl, dr);
    const int rt = ii % 5, rm = (ii + 1) % 5, rb = (ii + 2) % 5;
    union { bf16x4 v; bf16 e[4]; } o;
#pragma unroll
    for (int j = 0; j < 4; ++j) {
      float a = bs[j];
#pragma unroll
      for (int cx = 0; cx < 3; ++cx) {
        a = fmaf(win[rt][cx][j], wt[cx][j], a);
        a = fmaf(win[rm][cx][j], wt[3 + cx][j], a);
        a = fmaf(win[rb][cx][j], wt[6 + cx][j], a);
      }
      o.e[j] = f2b(geluf(a));
    }
    *(bf16x4*)(Yb + ((size_t)(y0 + ii) * HW + x) * (size_t)DH) = o.v;
  }
}

extern "C" void kernel_launch(void* const* d_in, const int* in_sizes, int n_in,
                              void* d_out, int out_size, void* d_ws, size_t ws_size,
                              hipStream_t stream) {
  (void)in_sizes; (void)n_in; (void)out_size; (void)ws_size;
  const float* x       = (const float*)d_in[0];
  const float* in_proj = (const float*)d_in[1];
  const float* wq_w = (const float*)d_in[2];   const float* wq_b = (const float*)d_in[3];
  const float* wk_w = (const float*)d_in[4];   const float* wk_b = (const float*)d_in[5];
  const float* wv_w = (const float*)d_in[6];   const float* wv_b = (const float*)d_in[7];
  const float* wo_w = (const float*)d_in[8];   const float* wo_b = (const float*)d_in[9];
  const float* psi_w = (const float*)d_in[10]; const float* psi_b = (const float*)d_in[11];
  const float* dyt_g = (const float*)d_in[12]; const float* dyt_b = (const float*)d_in[13];
  const float* m1_w = (const float*)d_in[14];  const float* m1_b = (const float*)d_in[15];
  const float* m2_w = (const float*)d_in[16];  const float* m2_b = (const float*)d_in[17];
  const float* we_w = (const float*)d_in[18];  const float* we_b = (const float*)d_in[19];
  const float* dw_w = (const float*)d_in[20];  const float* dw_b = (const float*)d_in[21];
  const float* wp_w = (const float*)d_in[22];  const float* wp_b = (const float*)d_in[23];
  const float* wout = (const float*)d_in[24];
  float* out = (float*)d_out;

  char* ws = (char*)d_ws;
  const size_t MB = 1u << 20;
  // f32 activations
  float* H     = (float*)(ws);               // 0-32MB : h (dead after wo GEMM)
  float* T1    = (float*)(ws);               // 0-32MB : T1 (written by dyt1, after H dead; dead after scale_b16)
  float* A     = (float*)(ws + 32 * MB);     // 32-64  : a+h -> U2
  // attention-phase buffers (dead before EDFFN)
  bf16*  psiB  = (bf16*)(ws + 64 * MB);      // 64-80
  bf16*  numb  = (bf16*)(ws + 80 * MB);      // 80-96
  bf16*  phiQ  = (bf16*)(ws + 96 * MB);      // 96-112
  bf16*  Hb    = (bf16*)(ws + 112 * MB);     // 112-128
  bf16*  phiKT = (bf16*)(ws + 128 * MB);     // 128-144 [B][C][N]
  bf16*  VT    = (bf16*)(ws + 144 * MB);     // 144-160 [B][C][N]
  bf16*  QKVr  = (bf16*)(ws + 160 * MB);     // 160-208 [MM][768] (48MB, dead before kv GEMM)
  bf16*  kvpartB = (bf16*)(ws + 160 * MB);   // 160-176 [128][C][C] bf16 (after qkmath)
  // EDFFN overlays
  bf16*  e1    = (bf16*)(ws + 64 * MB);      // 64-128 (64MB; attention bf16 bufs dead)
  bf16*  e2    = (bf16*)(ws + 128 * MB);     // 128-192 (64MB)
  float* T2    = (float*)(ws + 64 * MB);     // 64-96  (e1 dead after dwconv1024)
  bf16*  U1b   = (bf16*)(ws + 192 * MB);     // 192-208 (QKVr dead by scale_b16)
  // bf16 weights (persistent) 208-210
  bf16* wqkvb = (bf16*)(ws + 208 * MB);      // 384KB [768][256]
  bf16* wob   = wqkvb + 196608;              // 128KB
  bf16* web   = wob + 65536;                 // 512KB [1024][256]
  bf16* wpb   = web + 262144;                // 512KB [256][1024]
  float* bqkv = (float*)(wpb + 262144);      // 3KB
  float* pose = (float*)(ws + 210 * MB);     // 210-214
  char*  small = ws + 214 * MB;
  float* ksum  = (float*)(small);                 // 8KB
  float* rden  = (float*)(small + 64 * 1024);     // 128KB
  float* pool16 = (float*)(small + 192 * 1024);   // 128KB [8][16][256]
  float* gate1 = (float*)(small + 704 * 1024);
  float* gate2 = (float*)(small + 720 * 1024);
  bf16*  kvTb  = (bf16*)(small + 768 * 1024);     // 1MB [8][C][C]
  float* poolq = (float*)(ws + 216 * MB);         // 216-224 [8192][256] block partials

  dim3 blk(256);

  pos_kern<<<dim3(NN), blk, 0, stream>>>(pose);
  cvt_weights<<<dim3(1024, 6), blk, 0, stream>>>(wq_w, wk_w, wv_w, wo_w, we_w, wp_w,
                                                 wq_b, wk_b, wv_b,
                                                 wqkvb, wob, web, wpb, bqkv, ksum);
  inproj_tile<<<dim3(64, 4, BB), blk, 0, stream>>>(x, in_proj, H, Hb);

  // ---- attention ----
  dwconv_psi_v2<<<dim3(512), blk, 0, stream>>>(Hb, psi_w, psi_b, psiB);
  gemm_bf16<EPI_BIAS, false, false, true, bf16, float>
      <<<dim3(256, 6), blk, 0, stream>>>(Hb, wqkvb, bqkv, QKVr, CC, 768, nullptr, nullptr);
  qkmath_kern<<<dim3(MM / 64, 3), blk, 0, stream>>>(QKVr, pose, psiB, phiQ, phiKT, VT, ksum);
  gemm_bf16<EPI_PLAIN, false, true, false, bf16, float>
      <<<dim3(2, 2, 128), blk, 0, stream>>>(VT, phiKT, nullptr, kvpartB, NN, CC, nullptr, nullptr);
  kvred_kern<<<dim3(CC, BB), blk, 0, stream>>>(kvpartB, kvTb);
  den_kern<<<dim3(1024, BB), blk, 0, stream>>>(phiQ, ksum, rden);
  gemm_bf16<EPI_NUM, true, false, true, bf16, float>
      <<<dim3(256, 2), blk, 0, stream>>>(phiQ, kvTb, nullptr, numb, CC, CC, rden, nullptr);
  // wo GEMM with fused h-residual: A = wo_out + bias + H   (last read of H)
  gemm_bf16<EPI_ADD1, false, false, true, float, float>
      <<<dim3(256, 2), blk, 0, stream>>>(numb, wob, wo_b, A, CC, CC, nullptr, H);

  // ---- U1 = mona1(dyt(h + a)); T1 overwrites H region (H dead) ----
  dyt_kern<false><<<dim3(MM / 4), blk, 0, stream>>>(A, nullptr, dyt_g, dyt_b, T1, poolq);
  poolred_kern<<<dim3(16, BB), blk, 0, stream>>>(poolq, pool16);
  gate_kern<<<dim3(BB), blk, 0, stream>>>(pool16, m1_w, m1_b, gate1);
  scale_b16<<<dim3(MM / 4), blk, 0, stream>>>(T1, gate1, U1b);   // U1b = bf16(T1*gate1)

  // ---- EDFFN, single pass over all 8 batches; U1b residual fused into wp ----
  gemm_bf16<EPI_BIAS, false, false, true, bf16, float>
      <<<dim3(256, 8), blk, 0, stream>>>(U1b, web, we_b, e1, CC, DH, nullptr, nullptr);
  dwconv1024_v2<<<dim3(2048), blk, 0, stream>>>(e1, dw_w, dw_b, e2);
  gemm_bf16<EPI_RESID, false, false, true, float, bf16>
      <<<dim3(256, 2), blk, 0, stream>>>(e2, wpb, wp_b, A, DH, CC, nullptr, U1b);

  // ---- Y = mona2(dyt(U2)); final scale fused into out_proj ----
  dyt_kern<false><<<dim3(MM / 4), blk, 0, stream>>>(A, nullptr, dyt_g, dyt_b, T2, poolq);
  poolred_kern<<<dim3(16, BB), blk, 0, stream>>>(poolq, pool16);
  gate_kern<<<dim3(BB), blk, 0, stream>>>(pool16, m2_w, m2_b, gate2);

  // ---- out_proj + SiLU, transposed write; Y = T2*gate2 applied during staging ----
  outproj_tile<<<dim3(64, 1, BB), blk, 0, stream>>>(T2, gate2, wout, out);
}

// Round 19
// 439.066 us; speedup vs baseline: 1.0220x; 1.0145x over previous
//
#include <hip/hip_runtime.h>
#include <hip/hip_bf16.h>
#include <cmath>

using bf16 = __hip_bfloat16;
using bf16x8 = __attribute__((ext_vector_type(8))) short;
using bf16x4 = __attribute__((ext_vector_type(4))) short;
using f32x4v = __attribute__((ext_vector_type(4))) float;

static constexpr int BB  = 8;
static constexpr int HW  = 64;
static constexpr int NN  = HW * HW;     // 4096
static constexpr int CC  = 256;
static constexpr int CIN = 64;
static constexpr int DH  = 1024;
static constexpr int MM  = BB * NN;     // 32768

__device__ __forceinline__ bf16 f2b(float v) { return __float2bfloat16(v); }
__device__ __forceinline__ float b2f(bf16 v) { return __bfloat162float(v); }
__device__ __forceinline__ float tf(float v) { return v; }
__device__ __forceinline__ float tf(bf16 v)  { return b2f(v); }
__device__ __forceinline__ float frcp(float x) { return __builtin_amdgcn_rcpf(x); }
__device__ __forceinline__ float sigmf(float x) { return frcp(1.f + __expf(-x)); }
__device__ __forceinline__ float siluf(float x) { return x * sigmf(x); }
__device__ __forceinline__ float geluf(float x) {
  float z = x * fmaf(x * x, 0.07135481627f, 1.5957691216f);
  return x * sigmf(z);
}
__device__ __forceinline__ float tanhfast(float x) {
  return 1.f - 2.f * frcp(1.f + __expf(2.f * x));
}

// async global->LDS, 16B per lane; LDS dest must be linear in lane id.
__device__ __forceinline__ void stage16(const bf16* g, bf16* l) {
  __builtin_amdgcn_global_load_lds(
      (const __attribute__((address_space(1))) void*)g,
      (__attribute__((address_space(3))) void*)l, 16, 0, 0);
}

// ---------- pos table [N][C] ----------
__global__ __launch_bounds__(256) void pos_kern(float* __restrict__ pos) {
  int n = blockIdx.x, o = threadIdx.x;
  int yy = n >> 6, xx = n & 63;
  int i = o & 63, q = o >> 6;
  float omega = __expf((float)i * -0.14391156831212787f);  // 10000^(-i/64)
  float coord = (q < 2) ? (float)xx : (float)yy;
  float ang = coord * omega;
  pos[(size_t)n * CC + o] = (q & 1) ? __cosf(ang) : __sinf(ang);
}

// ---------- pre-convert weights to bf16 ----------
__global__ __launch_bounds__(256) void cvt_weights(
    const float* __restrict__ wq, const float* __restrict__ wk,
    const float* __restrict__ wv, const float* __restrict__ wo,
    const float* __restrict__ we, const float* __restrict__ wp,
    const float* __restrict__ qb, const float* __restrict__ kb,
    const float* __restrict__ vb,
    bf16* __restrict__ wqkvb, bf16* __restrict__ wob,
    bf16* __restrict__ web, bf16* __restrict__ wpb,
    float* __restrict__ bqkv, float* __restrict__ ksum) {
  int i = blockIdx.x * 256 + threadIdx.x;
  switch (blockIdx.y) {
    case 0: if (i < 65536) wqkvb[i] = f2b(wq[i]);
            if (i < 2048) ksum[i] = 0.f;
            break;
    case 1: if (i < 65536) wqkvb[65536 + i] = f2b(wk[i]);
            if (i < 768) bqkv[i] = (i < 256) ? qb[i] : (i < 512) ? kb[i - 256] : vb[i - 512];
            break;
    case 2: if (i < 65536) wqkvb[131072 + i] = f2b(wv[i]); break;
    case 3: if (i < 65536) wob[i] = f2b(wo[i]); break;
    case 4: web[i] = f2b(we[i]); break;  // 262144
    case 5: wpb[i] = f2b(wp[i]); break;  // 262144
  }
}

// ---------- in_proj: NCHW(64ch) -> [B*N,256] f32 + bf16, + SiLU ----------
__global__ __launch_bounds__(256) void inproj_tile(const float* __restrict__ X,
                                                   const float* __restrict__ W,
                                                   float* __restrict__ H,
                                                   bf16* __restrict__ Hb) {
  __shared__ float Xs[16][68];
  __shared__ float Ws[16][68];
  int m0 = blockIdx.x * 64, o0 = blockIdx.y * 64, b = blockIdx.z;
  int tid = threadIdx.x, tx = tid & 15, ty = tid >> 4;
  float acc[4][4] = {};
  for (int k0 = 0; k0 < CIN; k0 += 16) {
    {
      int mm = tid & 63, kk0 = tid >> 6;
#pragma unroll
      for (int i = 0; i < 4; ++i) {
        int kk = kk0 * 4 + i;
        Xs[kk][mm] = X[((size_t)(b * CIN + k0 + kk)) * NN + m0 + mm];
      }
    }
    {
      int kk = tid & 15, oo0 = tid >> 4;
#pragma unroll
      for (int i = 0; i < 4; ++i) {
        int oo = oo0 + i * 16;
        Ws[kk][oo] = W[(size_t)(o0 + oo) * CIN + k0 + kk];
      }
    }
    __syncthreads();
#pragma unroll
    for (int kk = 0; kk < 16; ++kk) {
      float xv[4], wv[4];
#pragma unroll
      for (int a = 0; a < 4; ++a) xv[a] = Xs[kk][ty * 4 + a];
#pragma unroll
      for (int c = 0; c < 4; ++c) wv[c] = Ws[kk][tx * 4 + c];
#pragma unroll
      for (int a = 0; a < 4; ++a)
#pragma unroll
        for (int c = 0; c < 4; ++c) acc[a][c] += xv[a] * wv[c];
    }
    __syncthreads();
  }
#pragma unroll
  for (int a = 0; a < 4; ++a) {
    int m = m0 + ty * 4 + a;
#pragma unroll
    for (int c = 0; c < 4; ++c) {
      int o = o0 + tx * 4 + c;
      float v = siluf(acc[a][c]);
      size_t idx = ((size_t)b * NN + m) * CC + o;
      H[idx] = v;
      Hb[idx] = f2b(v);
    }
  }
}

// ---------- out_proj: stages dyt(A,stats2)*gate2 inline (bit-identical to stored T2) ----------
__global__ __launch_bounds__(256) void outproj_tile(const float* __restrict__ A,
                                                    const float2* __restrict__ stats,
                                                    const float* __restrict__ gate,
                                                    const float* __restrict__ gdyt,
                                                    const float* __restrict__ bdyt,
                                                    const float* __restrict__ W,
                                                    float* __restrict__ Y) {
  __shared__ float Xs[16][68];
  __shared__ float Ws[16][68];
  int n0 = blockIdx.x * 64, b = blockIdx.z;
  size_t mbase = (size_t)b * NN;
  const float* gb = gate + b * CC;
  int tid = threadIdx.x, tx = tid & 15, ty = tid >> 4;
  float acc[4][4] = {};
  for (int k0 = 0; k0 < CC; k0 += 16) {
    int kk = tid & 15, rr0 = tid >> 4;
    float gk = gb[k0 + kk];
    float gd = gdyt[k0 + kk];
    float bd = bdyt[k0 + kk];
#pragma unroll
    for (int i = 0; i < 4; ++i) {
      int rr = rr0 + i * 16;
      size_t m = mbase + n0 + rr;
      float2 st = stats[m];
      float xv = A[m * CC + k0 + kk];
      Xs[kk][rr] = tanhfast(fmaf(gd * (xv - st.x), st.y, bd)) * gk;
      Ws[kk][rr] = (rr < CIN) ? W[(size_t)rr * CC + k0 + kk] : 0.f;
    }
    __syncthreads();
#pragma unroll
    for (int kk2 = 0; kk2 < 16; ++kk2) {
      float xv[4], wv[4];
#pragma unroll
      for (int a = 0; a < 4; ++a) xv[a] = Xs[kk2][ty * 4 + a];
#pragma unroll
      for (int c = 0; c < 4; ++c) wv[c] = Ws[kk2][tx * 4 + c];
#pragma unroll
      for (int a = 0; a < 4; ++a)
#pragma unroll
        for (int c = 0; c < 4; ++c) acc[a][c] += xv[a] * wv[c];
    }
    __syncthreads();
  }
#pragma unroll
  for (int a = 0; a < 4; ++a) {
    int n = n0 + ty * 4 + a;
#pragma unroll
    for (int c = 0; c < 4; ++c) {
      int o = tx * 4 + c;
      if (o < CIN)
        Y[(size_t)(b * CIN + o) * NN + n] = siluf(acc[a][c]);
    }
  }
}

// ---------- pure-bf16 MFMA GEMM core, global_load_lds staging, fused epilogues ----------
enum { EPI_PLAIN = 0, EPI_BIAS = 1, EPI_NUM = 3, EPI_RESID = 4, EPI_ADD1 = 5 };

__device__ __forceinline__ void storeO(float* p, float v) { *p = v; }
__device__ __forceinline__ void storeO(bf16* p, float v) { *p = f2b(v); }

// KVS: per-batch split-16 kv mode (z = b*16+ks)
// XSWZ: bijective XCD-chunked swizzle — blocks sharing an A m-tile co-locate on one XCD.
// EPI_RESID: v + 2*aux2[m][o]  (U1b bf16 residual)
template <int EPI, bool WPB, bool KVS, bool XSWZ, typename YT, typename A2T>
__global__ __launch_bounds__(256) void gemm_bf16(const bf16* __restrict__ X,
                                                 const bf16* __restrict__ W,
                                                 const float* __restrict__ bias,
                                                 YT* __restrict__ Y, int Kd, int Od,
                                                 const float* __restrict__ aux1,   // rden
                                                 const A2T* __restrict__ aux2) {   // H | U1b
  __shared__ __align__(16) bf16 As[128 * 32];
  __shared__ __align__(16) bf16 Bs[128 * 32];
  int m0, o0;
  if (XSWZ) {
    int gy = gridDim.y;
    int nwg = gridDim.x * gy;
    int lin = blockIdx.y * gridDim.x + blockIdx.x;
    int q = nwg >> 3;
    int lin2 = (lin & 7) * q + (lin >> 3);
    m0 = (lin2 / gy) * 128;
    o0 = (lin2 % gy) * 128;
  } else {
    m0 = blockIdx.x * 128;
    o0 = blockIdx.y * 128;
  }
  int kbeg = 0, kend = Kd;
  if (KVS) {
    int b = blockIdx.z >> 4, ks = blockIdx.z & 15;
    size_t off = (size_t)b * CC * Kd;
    X += off; W += off;
    Y += (size_t)blockIdx.z * CC * CC;
    kbeg = ks * (Kd / 16); kend = kbeg + Kd / 16;
  }
  const bf16* Wp = WPB ? (W + (size_t)(m0 >> 12) * Kd * Od) : W;
  int t = threadIdx.x;
  int l = t & 63, w = t >> 6;
  int wm = (w >> 1) * 64, wn = (w & 1) * 64;
  int lr = l & 15, lq = l >> 4;
  int srow = t >> 2, skc = (t & 3) * 8;
  f32x4v acc[4][4] = {};
  for (int k0 = kbeg; k0 < kend; k0 += 32) {
    stage16(X + (size_t)(m0 + srow) * Kd + k0 + skc, As + t * 8);
    stage16(X + (size_t)(m0 + 64 + srow) * Kd + k0 + skc, As + 2048 + t * 8);
    stage16(Wp + (size_t)(o0 + srow) * Kd + k0 + skc, Bs + t * 8);
    stage16(Wp + (size_t)(o0 + 64 + srow) * Kd + k0 + skc, Bs + 2048 + t * 8);
    __syncthreads();
    bf16x8 af[4], bfr[4];
#pragma unroll
    for (int mt = 0; mt < 4; ++mt)
      af[mt] = *(const bf16x8*)(As + (wm + mt * 16 + lr) * 32 + lq * 8);
#pragma unroll
    for (int nt = 0; nt < 4; ++nt)
      bfr[nt] = *(const bf16x8*)(Bs + (wn + nt * 16 + lr) * 32 + lq * 8);
#pragma unroll
    for (int mt = 0; mt < 4; ++mt)
#pragma unroll
      for (int nt = 0; nt < 4; ++nt)
        acc[mt][nt] = __builtin_amdgcn_mfma_f32_16x16x32_bf16(af[mt], bfr[nt], acc[mt][nt], 0, 0, 0);
    __syncthreads();
  }
  // C/D: col = lane&15 (o), row = (lane>>4)*4 + reg (m)
#pragma unroll
  for (int nt = 0; nt < 4; ++nt) {
    int o = o0 + wn + nt * 16 + lr;
    float bv = (EPI == EPI_PLAIN || EPI == EPI_NUM) ? 0.f : bias[o];
#pragma unroll
    for (int mt = 0; mt < 4; ++mt) {
      int mb = m0 + wm + mt * 16 + lq * 4;
#pragma unroll
      for (int r = 0; r < 4; ++r) {
        int m = mb + r;
        float v = acc[mt][nt][r] + bv;
        if constexpr (EPI == EPI_PLAIN || EPI == EPI_BIAS) {
          storeO(Y + (size_t)m * Od + o, v);
        } else if constexpr (EPI == EPI_NUM) {
          storeO(Y + (size_t)m * Od + o, v * aux1[m]);
        } else if constexpr (EPI == EPI_ADD1) {
          storeO(Y + (size_t)m * Od + o, v + tf(aux2[(size_t)m * Od + o]));
        } else {  // EPI_RESID: v + 2*U1b[m][o]
          storeO(Y + (size_t)m * Od + o, v + 2.f * tf(aux2[(size_t)m * Od + o]));
        }
      }
    }
  }
}

// ---------- QKV post-math: Q -> phiQ [m][c]; K -> KT [b][c][n] + ksum; V -> VT ----------
__global__ __launch_bounds__(256) void qkmath_kern(const bf16* __restrict__ QKV,  // [MM][768]
                                                   const float* __restrict__ pose,
                                                   const bf16* __restrict__ psi,
                                                   bf16* __restrict__ PQ,
                                                   bf16* __restrict__ KT,
                                                   bf16* __restrict__ VTo,
                                                   float* __restrict__ ksum) {
  __shared__ bf16 Ts[64][258];   // row stride 516B = 129 dwords (odd): conflict-free col reads
  int sec = blockIdx.y;
  int m0 = blockIdx.x * 64;
  int b = m0 >> 12, n0 = m0 & (NN - 1);
  int t = threadIdx.x;
  int cg = (t & 31) * 8;   // col group
  int rg = t >> 5;         // row sub-index
  if (sec == 0) {
#pragma unroll
    for (int p = 0; p < 8; ++p) {
      int r = p * 8 + rg;
      size_t m = (size_t)m0 + r;
      int n = (int)(m & (NN - 1));
      union { bf16x8 v; bf16 e[8]; } qv, pv, ov;
      qv.v = *(const bf16x8*)(QKV + m * 768 + cg);
      pv.v = *(const bf16x8*)(psi + m * CC + cg);
      const float* pr = pose + (size_t)n * CC + cg;
      f32x4v p0 = *(const f32x4v*)pr;
      f32x4v p1 = *(const f32x4v*)(pr + 4);
#pragma unroll
      for (int j = 0; j < 8; ++j) {
        float pj = (j < 4) ? p0[j] : p1[j - 4];
        float v = (b2f(qv.e[j]) + pj) * b2f(pv.e[j]);
        v = fmaxf(v, 0.f);
        ov.e[j] = f2b(v * v);
      }
      *(bf16x8*)(PQ + m * CC + cg) = ov.v;
    }
    return;
  }
  const bool KM = (sec == 1);
#pragma unroll
  for (int p = 0; p < 8; ++p) {
    int r = p * 8 + rg;
    size_t m = (size_t)m0 + r;
    union { bf16x8 v; bf16 e[8]; } qv, ov;
    qv.v = *(const bf16x8*)(QKV + m * 768 + sec * 256 + cg);
    if (KM) {
      int n = (int)(m & (NN - 1));
      union { bf16x8 v; bf16 e[8]; } pv;
      pv.v = *(const bf16x8*)(psi + m * CC + cg);
      const float* pr = pose + (size_t)n * CC + cg;
      f32x4v p0 = *(const f32x4v*)pr;
      f32x4v p1 = *(const f32x4v*)(pr + 4);
#pragma unroll
      for (int j = 0; j < 8; ++j) {
        float pj = (j < 4) ? p0[j] : p1[j - 4];
        float v = (b2f(qv.e[j]) + pj) * b2f(pv.e[j]);
        v = fmaxf(v, 0.f);
        ov.e[j] = f2b(v * v);
      }
    } else {
      ov.v = qv.v;   // V: pass bf16 bits through unchanged
    }
    *(bf16x8*)(&Ts[r][cg]) = ov.v;
  }
  __syncthreads();
  int wv = t >> 6, lane = t & 63;
  bf16* base = KM ? KT : VTo;
  int nloc = (lane & 7) * 8;
  int gsub = lane >> 3;
#pragma unroll
  for (int k = 0; k < 8; ++k) {
    int c = wv * 64 + k * 8 + gsub;
    union { bf16x8 v; bf16 e[8]; } pk;
#pragma unroll
    for (int i = 0; i < 8; ++i) pk.e[i] = Ts[nloc + i][c];
    *(bf16x8*)(base + ((size_t)(b * CC + c)) * NN + n0 + nloc) = pk.v;
    if (KM) {
      float s = 0.f;
#pragma unroll
      for (int i = 0; i < 8; ++i) s += b2f(pk.e[i]);
      s += __shfl_xor(s, 1);
      s += __shfl_xor(s, 2);
      s += __shfl_xor(s, 4);
      if ((lane & 7) == 0) atomicAdd(&ksum[b * CC + c], s);
    }
  }
}

// ---------- kvTb[b][d][c] = bf16(sum_ks kvpartB[b*16+ks][d][c]) (bf16 partials) ----------
__global__ __launch_bounds__(256) void kvred_kern(const bf16* __restrict__ part,
                                                  bf16* __restrict__ kvTb) {
  int d = blockIdx.x, b = blockIdx.y, c = threadIdx.x;
  float s = 0.f;
#pragma unroll
  for (int ks = 0; ks < 16; ++ks)
    s += b2f(part[((size_t)(b * 16 + ks) * CC + d) * CC + c]);
  kvTb[((size_t)b * CC + d) * CC + c] = f2b(s);
}

// ---------- rden: 1 row per wave, 4 rows per block ----------
__global__ __launch_bounds__(256) void den_kern(const bf16* __restrict__ PQ,
                                                const float* __restrict__ ksum,
                                                float* __restrict__ rden) {
  int b = blockIdx.y;
  int n = blockIdx.x * 4 + (threadIdx.x >> 6);
  int lane = threadIdx.x & 63;
  size_t m = (size_t)b * NN + n;
  union { bf16x4 v; bf16 e[4]; } u;
  u.v = *(const bf16x4*)(PQ + m * CC + lane * 4);
  const float* ks = ksum + b * CC + lane * 4;
  float s = 0.f;
#pragma unroll
  for (int j = 0; j < 4; ++j) s += b2f(u.e[j]) * ks[j];
#pragma unroll
  for (int off = 32; off >= 1; off >>= 1) s += __shfl_down(s, off);
  if (lane == 0) rden[m] = 1.f / (s + 1e-5f);
}

// ---------- DyT stats pass: per-row (mu, rs) + pool partial; no T write ----------
__global__ __launch_bounds__(256) void dytstat_kern(const float* __restrict__ X,
                                                    const float* __restrict__ g,
                                                    const float* __restrict__ bt,
                                                    float2* __restrict__ stats,
                                                    float* __restrict__ poolq) {
  int wv = threadIdx.x >> 6;
  int m = blockIdx.x * 4 + wv;
  int lane = threadIdx.x & 63;
  size_t base = (size_t)m * CC + lane * 4;
  f32x4v x = *(const f32x4v*)(X + base);
  float s = (x[0] + x[1]) + (x[2] + x[3]);
  float q = fmaf(x[0], x[0], fmaf(x[1], x[1], fmaf(x[2], x[2], x[3] * x[3])));
#pragma unroll
  for (int off = 32; off >= 1; off >>= 1) {
    s += __shfl_xor(s, off);
    q += __shfl_xor(q, off);
  }
  float mu = s * (1.f / 256.f);
  float var = (q - 256.f * mu * mu) * (1.f / 255.f);
  float sd = sqrtf(fmaxf(var, 0.f)) + 1e-5f;
  float rs = frcp(sd);
  if (lane == 0) stats[m] = make_float2(mu, rs);
  f32x4v gv = *(const f32x4v*)(g + lane * 4);
  f32x4v bv = *(const f32x4v*)(bt + lane * 4);
  f32x4v o;
#pragma unroll
  for (int j = 0; j < 4; ++j)
    o[j] = tanhfast(fmaf(gv[j] * (x[j] - mu), rs, bv[j]));
  __shared__ float ps[4][260];
#pragma unroll
  for (int j = 0; j < 4; ++j) ps[wv][lane * 4 + j] = o[j];
  __syncthreads();
  if (wv == 0) {
    f32x4v pv;
#pragma unroll
    for (int j = 0; j < 4; ++j) {
      int c = lane * 4 + j;
      pv[j] = (ps[0][c] + ps[1][c]) + (ps[2][c] + ps[3][c]);
    }
    *(f32x4v*)(poolq + (size_t)blockIdx.x * 256 + lane * 4) = pv;
  }
}

// ---------- poolred: pool16[(b*16+s)][c] = sum of 64 block-partials ----------
__global__ __launch_bounds__(256) void poolred_kern(const float* __restrict__ poolq,
                                                    float* __restrict__ pool16) {
  int s = blockIdx.x, b = blockIdx.y, c = threadIdx.x;
  float acc = 0.f;
#pragma unroll 8
  for (int k = 0; k < 64; ++k)
    acc += poolq[((size_t)(b * 1024 + s * 64 + k)) * 256 + c];
  pool16[(size_t)(b * 16 + s) * 256 + c] = acc;
}

// ---------- gate[b][o] = sigmoid(m_w . pool[b]/4096 + m_b) ----------
__global__ __launch_bounds__(256) void gate_kern(const float* __restrict__ pool16,
                                                 const float* __restrict__ w,
                                                 const float* __restrict__ bias,
                                                 float* __restrict__ gate) {
  int b = blockIdx.x, o = threadIdx.x;
  __shared__ float p[CC];
  float s = 0.f;
#pragma unroll
  for (int k = 0; k < 16; ++k) s += pool16[(size_t)(b * 16 + k) * 256 + o];
  p[o] = s * (1.f / 4096.f);
  __syncthreads();
  float acc = bias[o];
  for (int c = 0; c < CC; ++c) acc += p[c] * w[o * CC + c];
  gate[b * CC + o] = sigmf(acc);
}

// ---------- U1b = bf16(dyt(A,stats1)*gate1) (bit-identical to stored-T1 path) ----------
__global__ __launch_bounds__(256) void scale_from_A(const float* __restrict__ X,
                                                    const float2* __restrict__ stats,
                                                    const float* __restrict__ gate,
                                                    const float* __restrict__ g,
                                                    const float* __restrict__ bt,
                                                    bf16* __restrict__ Ob) {
  int wv = threadIdx.x >> 6;
  int m = blockIdx.x * 4 + wv;
  int lane = threadIdx.x & 63;
  int b = m >> 12;
  size_t base = (size_t)m * CC + lane * 4;
  f32x4v x = *(const f32x4v*)(X + base);
  float2 st = stats[m];
  f32x4v gv = *(const f32x4v*)(g + lane * 4);
  f32x4v bv = *(const f32x4v*)(bt + lane * 4);
  f32x4v gg = *(const f32x4v*)(gate + b * CC + lane * 4);
  union { bf16x4 v; bf16 e[4]; } ob;
#pragma unroll
  for (int j = 0; j < 4; ++j) {
    float tv = tanhfast(fmaf(gv[j] * (x[j] - st.x), st.y, bv[j]));
    ob.e[j] = f2b(tv * gg[j]);
  }
  *(bf16x4*)(Ob + base) = ob.v;
}

// ---------- depthwise 3x3 sliding-window helper (bf16 input, stride templated) ----------
template <int STRIDE>
__device__ __forceinline__ void dw_loadrow_b16(float (&row)[3][4], const bf16* __restrict__ Xb,
                                               int yy, int x, int dl, int dr) {
  if (yy < 0 || yy >= HW) {
#pragma unroll
    for (int cx = 0; cx < 3; ++cx)
#pragma unroll
      for (int j = 0; j < 4; ++j) row[cx][j] = 0.f;
    return;
  }
  const bf16* base = Xb + ((size_t)yy * HW + x) * (size_t)STRIDE;
  union U { bf16x4 v; bf16 e[4]; } um, ul, ur;
  um.v = *(const bf16x4*)base;
  ul.v = *(const bf16x4*)(base + dl);
  ur.v = *(const bf16x4*)(base + dr);
#pragma unroll
  for (int j = 0; j < 4; ++j) {
    row[0][j] = b2f(ul.e[j]);
    row[1][j] = b2f(um.e[j]);
    row[2][j] = b2f(ur.e[j]);
  }
}

// ---------- depthwise 3x3 + sigmoid, bf16 in (Hb) -> bf16 out (psi), 2-row load-ahead ----------
__global__ __launch_bounds__(256) void dwconv_psi_v2(const bf16* __restrict__ X,
                                                     const float* __restrict__ w,
                                                     const float* __restrict__ bias,
                                                     bf16* __restrict__ Y) {
  int i = blockIdx.x;
  int lin = (i & 7) * 64 + (i >> 3);
  int xg = lin & 15, yc = (lin >> 4) & 3, b = lin >> 6;
  int c0 = (threadIdx.x & 63) * 4;
  int x  = xg * 4 + (threadIdx.x >> 6);
  int y0 = yc * 16;
  const bf16* Xb = X + (size_t)b * NN * CC + c0;
  bf16* Yb      = Y + (size_t)b * NN * CC + c0;
  float wt[9][4], bs[4];
#pragma unroll
  for (int j = 0; j < 4; ++j) {
    bs[j] = bias[c0 + j];
#pragma unroll
    for (int t9 = 0; t9 < 9; ++t9) wt[t9][j] = w[(c0 + j) * 9 + t9];
  }
  const bool xl = (x > 0), xr = (x < HW - 1);
  if (!xl) {
#pragma unroll
    for (int j = 0; j < 4; ++j) wt[0][j] = wt[3][j] = wt[6][j] = 0.f;
  }
  if (!xr) {
#pragma unroll
    for (int j = 0; j < 4; ++j) wt[2][j] = wt[5][j] = wt[8][j] = 0.f;
  }
  const int dl = xl ? -CC : 0, dr = xr ? CC : 0;
  float win[5][3][4];
  dw_loadrow_b16<CC>(win[0], Xb, y0 - 1, x, dl, dr);
  dw_loadrow_b16<CC>(win[1], Xb, y0,     x, dl, dr);
  dw_loadrow_b16<CC>(win[2], Xb, y0 + 1, x, dl, dr);
  dw_loadrow_b16<CC>(win[3], Xb, y0 + 2, x, dl, dr);
#pragma unroll
  for (int ii = 0; ii < 16; ++ii) {
    dw_loadrow_b16<CC>(win[(ii + 4) % 5], Xb, y0 + ii + 3, x, dl, dr);
    const int rt = ii % 5, rm = (ii + 1) % 5, rb = (ii + 2) % 5;
    union { bf16x4 v; bf16 e[4]; } o;
#pragma unroll
    for (int j = 0; j < 4; ++j) {
      float a = bs[j];
#pragma unroll
      for (int cx = 0; cx < 3; ++cx) {
        a = fmaf(win[rt][cx][j], wt[cx][j], a);
        a = fmaf(win[rm][cx][j], wt[3 + cx][j], a);
        a = fmaf(win[rb][cx][j], wt[6 + cx][j], a);
      }
      o.e[j] = f2b(sigmf(a));
    }
    *(bf16x4*)(Yb + ((size_t)(y0 + ii) * HW + x) * (size_t)CC) = o.v;
  }
}

// ---------- depthwise 3x3 + gelu, bf16 in/out (1024ch), 2-row load-ahead ----------
__global__ __launch_bounds__(256) void dwconv1024_v2(const bf16* __restrict__ X,
                                                     const float* __restrict__ w,
                                                     const float* __restrict__ bias,
                                                     bf16* __restrict__ Y) {
  int i = blockIdx.x;
  int lin = (i & 7) * 256 + (i >> 3);
  int x = lin & 63, yc = (lin >> 6) & 3, b = lin >> 8;
  int c0 = threadIdx.x * 4;
  int y0 = yc * 16;
  const bf16* Xb = X + (size_t)b * NN * DH + c0;
  bf16* Yb       = Y + (size_t)b * NN * DH + c0;
  float wt[9][4], bs[4];
#pragma unroll
  for (int j = 0; j < 4; ++j) {
    bs[j] = bias[c0 + j];
#pragma unroll
    for (int t9 = 0; t9 < 9; ++t9) wt[t9][j] = w[(c0 + j) * 9 + t9];
  }
  const bool xl = (x > 0), xr = (x < HW - 1);
  if (!xl) {
#pragma unroll
    for (int j = 0; j < 4; ++j) wt[0][j] = wt[3][j] = wt[6][j] = 0.f;
  }
  if (!xr) {
#pragma unroll
    for (int j = 0; j < 4; ++j) wt[2][j] = wt[5][j] = wt[8][j] = 0.f;
  }
  const int dl = xl ? -DH : 0, dr = xr ? DH : 0;
  float win[5][3][4];
  dw_loadrow_b16<DH>(win[0], Xb, y0 - 1, x, dl, dr);
  dw_loadrow_b16<DH>(win[1], Xb, y0,     x, dl, dr);
  dw_loadrow_b16<DH>(win[2], Xb, y0 + 1, x, dl, dr);
  dw_loadrow_b16<DH>(win[3], Xb, y0 + 2, x, dl, dr);
#pragma unroll
  for (int ii = 0; ii < 16; ++ii) {
    dw_loadrow_b16<DH>(win[(ii + 4) % 5], Xb, y0 + ii + 3, x, dl, dr);
    const int rt = ii % 5, rm = (ii + 1) % 5, rb = (ii + 2) % 5;
    union { bf16x4 v; bf16 e[4]; } o;
#pragma unroll
    for (int j = 0; j < 4; ++j) {
      float a = bs[j];
#pragma unroll
      for (int cx = 0; cx < 3; ++cx) {
        a = fmaf(win[rt][cx][j], wt[cx][j], a);
        a = fmaf(win[rm][cx][j], wt[3 + cx][j], a);
        a = fmaf(win[rb][cx][j], wt[6 + cx][j], a);
      }
      o.e[j] = f2b(geluf(a));
    }
    *(bf16x4*)(Yb + ((size_t)(y0 + ii) * HW + x) * (size_t)DH) = o.v;
  }
}

extern "C" void kernel_launch(void* const* d_in, const int* in_sizes, int n_in,
                              void* d_out, int out_size, void* d_ws, size_t ws_size,
                              hipStream_t stream) {
  (void)in_sizes; (void)n_in; (void)out_size; (void)ws_size;
  const float* x       = (const float*)d_in[0];
  const float* in_proj = (const float*)d_in[1];
  const float* wq_w = (const float*)d_in[2];   const float* wq_b = (const float*)d_in[3];
  const float* wk_w = (const float*)d_in[4];   const float* wk_b = (const float*)d_in[5];
  const float* wv_w = (const float*)d_in[6];   const float* wv_b = (const float*)d_in[7];
  const float* wo_w = (const float*)d_in[8];   const float* wo_b = (const float*)d_in[9];
  const float* psi_w = (const float*)d_in[10]; const float* psi_b = (const float*)d_in[11];
  const float* dyt_g = (const float*)d_in[12]; const float* dyt_b = (const float*)d_in[13];
  const float* m1_w = (const float*)d_in[14];  const float* m1_b = (const float*)d_in[15];
  const float* m2_w = (const float*)d_in[16];  const float* m2_b = (const float*)d_in[17];
  const float* we_w = (const float*)d_in[18];  const float* we_b = (const float*)d_in[19];
  const float* dw_w = (const float*)d_in[20];  const float* dw_b = (const float*)d_in[21];
  const float* wp_w = (const float*)d_in[22];  const float* wp_b = (const float*)d_in[23];
  const float* wout = (const float*)d_in[24];
  float* out = (float*)d_out;

  char* ws = (char*)d_ws;
  const size_t MB = 1u << 20;
  // f32 activations
  float* H     = (float*)(ws);               // 0-32MB : h (dead after wo GEMM)
  float* A     = (float*)(ws + 32 * MB);     // 32-64  : a+h -> U2 (alive to the end)
  // attention-phase buffers (dead before EDFFN)
  bf16*  psiB  = (bf16*)(ws + 64 * MB);      // 64-80
  bf16*  numb  = (bf16*)(ws + 80 * MB);      // 80-96
  bf16*  phiQ  = (bf16*)(ws + 96 * MB);      // 96-112
  bf16*  Hb    = (bf16*)(ws + 112 * MB);     // 112-128
  bf16*  phiKT = (bf16*)(ws + 128 * MB);     // 128-144 [B][C][N]
  bf16*  VT    = (bf16*)(ws + 144 * MB);     // 144-160 [B][C][N]
  bf16*  QKVr  = (bf16*)(ws + 160 * MB);     // 160-208 [MM][768] (48MB, dead before kv GEMM)
  bf16*  kvpartB = (bf16*)(ws + 160 * MB);   // 160-176 [128][C][C] bf16 (after qkmath)
  // EDFFN overlays
  bf16*  e1    = (bf16*)(ws + 64 * MB);      // 64-128 (64MB; attention bf16 bufs dead)
  bf16*  e2    = (bf16*)(ws + 128 * MB);     // 128-192 (64MB)
  bf16*  U1b   = (bf16*)(ws + 192 * MB);     // 192-208 (QKVr dead by scale_from_A)
  // bf16 weights (persistent) 208-210
  bf16* wqkvb = (bf16*)(ws + 208 * MB);      // 384KB [768][256]
  bf16* wob   = wqkvb + 196608;              // 128KB
  bf16* web   = wob + 65536;                 // 512KB [1024][256]
  bf16* wpb   = web + 262144;                // 512KB [256][1024]
  float* bqkv = (float*)(wpb + 262144);      // 3KB
  float* pose = (float*)(ws + 210 * MB);     // 210-214
  char*  small = ws + 214 * MB;
  float* ksum  = (float*)(small);                 // 8KB
  float* rden  = (float*)(small + 64 * 1024);     // 128KB
  float* pool16 = (float*)(small + 192 * 1024);   // 128KB [8][16][256]
  float* gate1 = (float*)(small + 704 * 1024);
  float* gate2 = (float*)(small + 720 * 1024);
  bf16*  kvTb  = (bf16*)(small + 768 * 1024);     // 1MB [8][C][C]
  float* poolq = (float*)(ws + 216 * MB);         // 216-224 [8192][256] block partials
  float2* stats1 = (float2*)(ws + 224 * MB);      // 256KB [MM] (mu, rs)
  float2* stats2 = (float2*)(ws + 225 * MB);      // 256KB [MM]

  dim3 blk(256);

  pos_kern<<<dim3(NN), blk, 0, stream>>>(pose);
  cvt_weights<<<dim3(1024, 6), blk, 0, stream>>>(wq_w, wk_w, wv_w, wo_w, we_w, wp_w,
                                                 wq_b, wk_b, wv_b,
                                                 wqkvb, wob, web, wpb, bqkv, ksum);
  inproj_tile<<<dim3(64, 4, BB), blk, 0, stream>>>(x, in_proj, H, Hb);

  // ---- attention ----
  dwconv_psi_v2<<<dim3(512), blk, 0, stream>>>(Hb, psi_w, psi_b, psiB);
  gemm_bf16<EPI_BIAS, false, false, true, bf16, float>
      <<<dim3(256, 6), blk, 0, stream>>>(Hb, wqkvb, bqkv, QKVr, CC, 768, nullptr, nullptr);
  qkmath_kern<<<dim3(MM / 64, 3), blk, 0, stream>>>(QKVr, pose, psiB, phiQ, phiKT, VT, ksum);
  gemm_bf16<EPI_PLAIN, false, true, false, bf16, float>
      <<<dim3(2, 2, 128), blk, 0, stream>>>(VT, phiKT, nullptr, kvpartB, NN, CC, nullptr, nullptr);
  kvred_kern<<<dim3(CC, BB), blk, 0, stream>>>(kvpartB, kvTb);
  den_kern<<<dim3(1024, BB), blk, 0, stream>>>(phiQ, ksum, rden);
  gemm_bf16<EPI_NUM, true, false, true, bf16, float>
      <<<dim3(256, 2), blk, 0, stream>>>(phiQ, kvTb, nullptr, numb, CC, CC, rden, nullptr);
  // wo GEMM with fused h-residual: A = wo_out + bias + H   (last read of H)
  gemm_bf16<EPI_ADD1, false, false, true, float, float>
      <<<dim3(256, 2), blk, 0, stream>>>(numb, wob, wo_b, A, CC, CC, nullptr, H);

  // ---- U1 = mona1(dyt(A)); stats-only DyT, U1b recomputed from A ----
  dytstat_kern<<<dim3(MM / 4), blk, 0, stream>>>(A, dyt_g, dyt_b, stats1, poolq);
  poolred_kern<<<dim3(16, BB), blk, 0, stream>>>(poolq, pool16);
  gate_kern<<<dim3(BB), blk, 0, stream>>>(pool16, m1_w, m1_b, gate1);
  scale_from_A<<<dim3(MM / 4), blk, 0, stream>>>(A, stats1, gate1, dyt_g, dyt_b, U1b);

  // ---- EDFFN, single pass over all 8 batches; U1b residual fused into wp ----
  gemm_bf16<EPI_BIAS, false, false, true, bf16, float>
      <<<dim3(256, 8), blk, 0, stream>>>(U1b, web, we_b, e1, CC, DH, nullptr, nullptr);
  dwconv1024_v2<<<dim3(2048), blk, 0, stream>>>(e1, dw_w, dw_b, e2);
  gemm_bf16<EPI_RESID, false, false, true, float, bf16>
      <<<dim3(256, 2), blk, 0, stream>>>(e2, wpb, wp_b, A, DH, CC, nullptr, U1b);

  // ---- Y = mona2(dyt(U2)); stats-only DyT, dyt recomputed in out_proj staging ----
  dytstat_kern<<<dim3(MM / 4), blk, 0, stream>>>(A, dyt_g, dyt_b, stats2, poolq);
  poolred_kern<<<dim3(16, BB), blk, 0, stream>>>(poolq, pool16);
  gate_kern<<<dim3(BB), blk, 0, stream>>>(pool16, m2_w, m2_b, gate2);

  // ---- out_proj + SiLU, transposed write; dyt(A)*gate2 applied during staging ----
  outproj_tile<<<dim3(64, 1, BB), blk, 0, stream>>>(A, stats2, gate2, dyt_g, dyt_b, wout, out);
}

// Round 20
// 422.394 us; speedup vs baseline: 1.0624x; 1.0395x over previous
//
#include <hip/hip_runtime.h>
#include <hip/hip_bf16.h>
#include <cmath>

using bf16 = __hip_bfloat16;
using bf16x8 = __attribute__((ext_vector_type(8))) short;
using bf16x4 = __attribute__((ext_vector_type(4))) short;
using f32x4v = __attribute__((ext_vector_type(4))) float;

static constexpr int BB  = 8;
static constexpr int HW  = 64;
static constexpr int NN  = HW * HW;     // 4096
static constexpr int CC  = 256;
static constexpr int CIN = 64;
static constexpr int DH  = 1024;
static constexpr int MM  = BB * NN;     // 32768

__device__ __forceinline__ bf16 f2b(float v) { return __float2bfloat16(v); }
__device__ __forceinline__ float b2f(bf16 v) { return __bfloat162float(v); }
__device__ __forceinline__ float tf(float v) { return v; }
__device__ __forceinline__ float tf(bf16 v)  { return b2f(v); }
__device__ __forceinline__ float frcp(float x) { return __builtin_amdgcn_rcpf(x); }
__device__ __forceinline__ float sigmf(float x) { return frcp(1.f + __expf(-x)); }
__device__ __forceinline__ float siluf(float x) { return x * sigmf(x); }
__device__ __forceinline__ float geluf(float x) {
  float z = x * fmaf(x * x, 0.07135481627f, 1.5957691216f);
  return x * sigmf(z);
}
__device__ __forceinline__ float tanhfast(float x) {
  return 1.f - 2.f * frcp(1.f + __expf(2.f * x));
}

// async global->LDS, 16B per lane; LDS dest must be linear in lane id.
__device__ __forceinline__ void stage16(const bf16* g, bf16* l) {
  __builtin_amdgcn_global_load_lds(
      (const __attribute__((address_space(1))) void*)g,
      (__attribute__((address_space(3))) void*)l, 16, 0, 0);
}

// ---------- pos table [N][C] ----------
__global__ __launch_bounds__(256) void pos_kern(float* __restrict__ pos) {
  int n = blockIdx.x, o = threadIdx.x;
  int yy = n >> 6, xx = n & 63;
  int i = o & 63, q = o >> 6;
  float omega = __expf((float)i * -0.14391156831212787f);  // 10000^(-i/64)
  float coord = (q < 2) ? (float)xx : (float)yy;
  float ang = coord * omega;
  pos[(size_t)n * CC + o] = (q & 1) ? __cosf(ang) : __sinf(ang);
}

// ---------- pre-convert weights to bf16 ----------
__global__ __launch_bounds__(256) void cvt_weights(
    const float* __restrict__ wq, const float* __restrict__ wk,
    const float* __restrict__ wv, const float* __restrict__ wo,
    const float* __restrict__ we, const float* __restrict__ wp,
    const float* __restrict__ qb, const float* __restrict__ kb,
    const float* __restrict__ vb,
    bf16* __restrict__ wqkvb, bf16* __restrict__ wob,
    bf16* __restrict__ web, bf16* __restrict__ wpb,
    float* __restrict__ bqkv, float* __restrict__ ksum) {
  int i = blockIdx.x * 256 + threadIdx.x;
  switch (blockIdx.y) {
    case 0: if (i < 65536) wqkvb[i] = f2b(wq[i]);
            if (i < 2048) ksum[i] = 0.f;
            break;
    case 1: if (i < 65536) wqkvb[65536 + i] = f2b(wk[i]);
            if (i < 768) bqkv[i] = (i < 256) ? qb[i] : (i < 512) ? kb[i - 256] : vb[i - 512];
            break;
    case 2: if (i < 65536) wqkvb[131072 + i] = f2b(wv[i]); break;
    case 3: if (i < 65536) wob[i] = f2b(wo[i]); break;
    case 4: web[i] = f2b(we[i]); break;  // 262144
    case 5: wpb[i] = f2b(wp[i]); break;  // 262144
  }
}

// ---------- in_proj: NCHW(64ch) -> [B*N,256] bf16 only, + SiLU ----------
__global__ __launch_bounds__(256) void inproj_tile(const float* __restrict__ X,
                                                   const float* __restrict__ W,
                                                   bf16* __restrict__ Hb) {
  __shared__ float Xs[16][68];
  __shared__ float Ws[16][68];
  int m0 = blockIdx.x * 64, o0 = blockIdx.y * 64, b = blockIdx.z;
  int tid = threadIdx.x, tx = tid & 15, ty = tid >> 4;
  float acc[4][4] = {};
  for (int k0 = 0; k0 < CIN; k0 += 16) {
    {
      int mm = tid & 63, kk0 = tid >> 6;
#pragma unroll
      for (int i = 0; i < 4; ++i) {
        int kk = kk0 * 4 + i;
        Xs[kk][mm] = X[((size_t)(b * CIN + k0 + kk)) * NN + m0 + mm];
      }
    }
    {
      int kk = tid & 15, oo0 = tid >> 4;
#pragma unroll
      for (int i = 0; i < 4; ++i) {
        int oo = oo0 + i * 16;
        Ws[kk][oo] = W[(size_t)(o0 + oo) * CIN + k0 + kk];
      }
    }
    __syncthreads();
#pragma unroll
    for (int kk = 0; kk < 16; ++kk) {
      float xv[4], wv[4];
#pragma unroll
      for (int a = 0; a < 4; ++a) xv[a] = Xs[kk][ty * 4 + a];
#pragma unroll
      for (int c = 0; c < 4; ++c) wv[c] = Ws[kk][tx * 4 + c];
#pragma unroll
      for (int a = 0; a < 4; ++a)
#pragma unroll
        for (int c = 0; c < 4; ++c) acc[a][c] += xv[a] * wv[c];
    }
    __syncthreads();
  }
#pragma unroll
  for (int a = 0; a < 4; ++a) {
    int m = m0 + ty * 4 + a;
#pragma unroll
    for (int c = 0; c < 4; ++c) {
      int o = o0 + tx * 4 + c;
      float v = siluf(acc[a][c]);
      Hb[((size_t)b * NN + m) * CC + o] = f2b(v);
    }
  }
}

// ---------- out_proj: stages dyt(A,stats2)*gate2 inline (bit-identical to stored T2) ----------
__global__ __launch_bounds__(256) void outproj_tile(const float* __restrict__ A,
                                                    const float2* __restrict__ stats,
                                                    const float* __restrict__ gate,
                                                    const float* __restrict__ gdyt,
                                                    const float* __restrict__ bdyt,
                                                    const float* __restrict__ W,
                                                    float* __restrict__ Y) {
  __shared__ float Xs[16][68];
  __shared__ float Ws[16][68];
  int n0 = blockIdx.x * 64, b = blockIdx.z;
  size_t mbase = (size_t)b * NN;
  const float* gb = gate + b * CC;
  int tid = threadIdx.x, tx = tid & 15, ty = tid >> 4;
  float acc[4][4] = {};
  for (int k0 = 0; k0 < CC; k0 += 16) {
    int kk = tid & 15, rr0 = tid >> 4;
    float gk = gb[k0 + kk];
    float gd = gdyt[k0 + kk];
    float bd = bdyt[k0 + kk];
#pragma unroll
    for (int i = 0; i < 4; ++i) {
      int rr = rr0 + i * 16;
      size_t m = mbase + n0 + rr;
      float2 st = stats[m];
      float xv = A[m * CC + k0 + kk];
      Xs[kk][rr] = tanhfast(fmaf(gd * (xv - st.x), st.y, bd)) * gk;
      Ws[kk][rr] = (rr < CIN) ? W[(size_t)rr * CC + k0 + kk] : 0.f;
    }
    __syncthreads();
#pragma unroll
    for (int kk2 = 0; kk2 < 16; ++kk2) {
      float xv[4], wv[4];
#pragma unroll
      for (int a = 0; a < 4; ++a) xv[a] = Xs[kk2][ty * 4 + a];
#pragma unroll
      for (int c = 0; c < 4; ++c) wv[c] = Ws[kk2][tx * 4 + c];
#pragma unroll
      for (int a = 0; a < 4; ++a)
#pragma unroll
        for (int c = 0; c < 4; ++c) acc[a][c] += xv[a] * wv[c];
    }
    __syncthreads();
  }
#pragma unroll
  for (int a = 0; a < 4; ++a) {
    int n = n0 + ty * 4 + a;
#pragma unroll
    for (int c = 0; c < 4; ++c) {
      int o = tx * 4 + c;
      if (o < CIN)
        Y[(size_t)(b * CIN + o) * NN + n] = siluf(acc[a][c]);
    }
  }
}

// ---------- pure-bf16 MFMA GEMM core, global_load_lds staging, fused epilogues ----------
enum { EPI_PLAIN = 0, EPI_BIAS = 1, EPI_NUM = 3, EPI_RESID = 4, EPI_ADD1 = 5 };

__device__ __forceinline__ void storeO(float* p, float v) { *p = v; }
__device__ __forceinline__ void storeO(bf16* p, float v) { *p = f2b(v); }

// KVS: per-batch split-16 kv mode (z = b*16+ks)
// XSWZ: bijective XCD-chunked swizzle — blocks sharing an A m-tile co-locate on one XCD.
// EPI_ADD1: v + aux2[m][o] (Hb residual); EPI_RESID: v + 2*aux2[m][o] (U1b residual)
template <int EPI, bool WPB, bool KVS, bool XSWZ, typename YT, typename A2T>
__global__ __launch_bounds__(256) void gemm_bf16(const bf16* __restrict__ X,
                                                 const bf16* __restrict__ W,
                                                 const float* __restrict__ bias,
                                                 YT* __restrict__ Y, int Kd, int Od,
                                                 const float* __restrict__ aux1,   // rden
                                                 const A2T* __restrict__ aux2) {   // Hb | U1b
  __shared__ __align__(16) bf16 As[128 * 32];
  __shared__ __align__(16) bf16 Bs[128 * 32];
  int m0, o0;
  if (XSWZ) {
    int gy = gridDim.y;
    int nwg = gridDim.x * gy;
    int lin = blockIdx.y * gridDim.x + blockIdx.x;
    int q = nwg >> 3;
    int lin2 = (lin & 7) * q + (lin >> 3);
    m0 = (lin2 / gy) * 128;
    o0 = (lin2 % gy) * 128;
  } else {
    m0 = blockIdx.x * 128;
    o0 = blockIdx.y * 128;
  }
  int kbeg = 0, kend = Kd;
  if (KVS) {
    int b = blockIdx.z >> 4, ks = blockIdx.z & 15;
    size_t off = (size_t)b * CC * Kd;
    X += off; W += off;
    Y += (size_t)blockIdx.z * CC * CC;
    kbeg = ks * (Kd / 16); kend = kbeg + Kd / 16;
  }
  const bf16* Wp = WPB ? (W + (size_t)(m0 >> 12) * Kd * Od) : W;
  int t = threadIdx.x;
  int l = t & 63, w = t >> 6;
  int wm = (w >> 1) * 64, wn = (w & 1) * 64;
  int lr = l & 15, lq = l >> 4;
  int srow = t >> 2, skc = (t & 3) * 8;
  f32x4v acc[4][4] = {};
  for (int k0 = kbeg; k0 < kend; k0 += 32) {
    stage16(X + (size_t)(m0 + srow) * Kd + k0 + skc, As + t * 8);
    stage16(X + (size_t)(m0 + 64 + srow) * Kd + k0 + skc, As + 2048 + t * 8);
    stage16(Wp + (size_t)(o0 + srow) * Kd + k0 + skc, Bs + t * 8);
    stage16(Wp + (size_t)(o0 + 64 + srow) * Kd + k0 + skc, Bs + 2048 + t * 8);
    __syncthreads();
    bf16x8 af[4], bfr[4];
#pragma unroll
    for (int mt = 0; mt < 4; ++mt)
      af[mt] = *(const bf16x8*)(As + (wm + mt * 16 + lr) * 32 + lq * 8);
#pragma unroll
    for (int nt = 0; nt < 4; ++nt)
      bfr[nt] = *(const bf16x8*)(Bs + (wn + nt * 16 + lr) * 32 + lq * 8);
#pragma unroll
    for (int mt = 0; mt < 4; ++mt)
#pragma unroll
      for (int nt = 0; nt < 4; ++nt)
        acc[mt][nt] = __builtin_amdgcn_mfma_f32_16x16x32_bf16(af[mt], bfr[nt], acc[mt][nt], 0, 0, 0);
    __syncthreads();
  }
  // C/D: col = lane&15 (o), row = (lane>>4)*4 + reg (m)
#pragma unroll
  for (int nt = 0; nt < 4; ++nt) {
    int o = o0 + wn + nt * 16 + lr;
    float bv = (EPI == EPI_PLAIN || EPI == EPI_NUM) ? 0.f : bias[o];
#pragma unroll
    for (int mt = 0; mt < 4; ++mt) {
      int mb = m0 + wm + mt * 16 + lq * 4;
#pragma unroll
      for (int r = 0; r < 4; ++r) {
        int m = mb + r;
        float v = acc[mt][nt][r] + bv;
        if constexpr (EPI == EPI_PLAIN || EPI == EPI_BIAS) {
          storeO(Y + (size_t)m * Od + o, v);
        } else if constexpr (EPI == EPI_NUM) {
          storeO(Y + (size_t)m * Od + o, v * aux1[m]);
        } else if constexpr (EPI == EPI_ADD1) {
          storeO(Y + (size_t)m * Od + o, v + tf(aux2[(size_t)m * Od + o]));
        } else {  // EPI_RESID: v + 2*U1b[m][o]
          storeO(Y + (size_t)m * Od + o, v + 2.f * tf(aux2[(size_t)m * Od + o]));
        }
      }
    }
  }
}

// ---------- QKV post-math: Q -> phiQ [m][c]; K -> KT [b][c][n] + ksum; V -> VT ----------
__global__ __launch_bounds__(256) void qkmath_kern(const bf16* __restrict__ QKV,  // [MM][768]
                                                   const float* __restrict__ pose,
                                                   const bf16* __restrict__ psi,
                                                   bf16* __restrict__ PQ,
                                                   bf16* __restrict__ KT,
                                                   bf16* __restrict__ VTo,
                                                   float* __restrict__ ksum) {
  __shared__ bf16 Ts[64][258];   // row stride 516B = 129 dwords (odd): conflict-free col reads
  int sec = blockIdx.y;
  int m0 = blockIdx.x * 64;
  int b = m0 >> 12, n0 = m0 & (NN - 1);
  int t = threadIdx.x;
  int cg = (t & 31) * 8;   // col group
  int rg = t >> 5;         // row sub-index
  if (sec == 0) {
#pragma unroll
    for (int p = 0; p < 8; ++p) {
      int r = p * 8 + rg;
      size_t m = (size_t)m0 + r;
      int n = (int)(m & (NN - 1));
      union { bf16x8 v; bf16 e[8]; } qv, pv, ov;
      qv.v = *(const bf16x8*)(QKV + m * 768 + cg);
      pv.v = *(const bf16x8*)(psi + m * CC + cg);
      const float* pr = pose + (size_t)n * CC + cg;
      f32x4v p0 = *(const f32x4v*)pr;
      f32x4v p1 = *(const f32x4v*)(pr + 4);
#pragma unroll
      for (int j = 0; j < 8; ++j) {
        float pj = (j < 4) ? p0[j] : p1[j - 4];
        float v = (b2f(qv.e[j]) + pj) * b2f(pv.e[j]);
        v = fmaxf(v, 0.f);
        ov.e[j] = f2b(v * v);
      }
      *(bf16x8*)(PQ + m * CC + cg) = ov.v;
    }
    return;
  }
  const bool KM = (sec == 1);
#pragma unroll
  for (int p = 0; p < 8; ++p) {
    int r = p * 8 + rg;
    size_t m = (size_t)m0 + r;
    union { bf16x8 v; bf16 e[8]; } qv, ov;
    qv.v = *(const bf16x8*)(QKV + m * 768 + sec * 256 + cg);
    if (KM) {
      int n = (int)(m & (NN - 1));
      union { bf16x8 v; bf16 e[8]; } pv;
      pv.v = *(const bf16x8*)(psi + m * CC + cg);
      const float* pr = pose + (size_t)n * CC + cg;
      f32x4v p0 = *(const f32x4v*)pr;
      f32x4v p1 = *(const f32x4v*)(pr + 4);
#pragma unroll
      for (int j = 0; j < 8; ++j) {
        float pj = (j < 4) ? p0[j] : p1[j - 4];
        float v = (b2f(qv.e[j]) + pj) * b2f(pv.e[j]);
        v = fmaxf(v, 0.f);
        ov.e[j] = f2b(v * v);
      }
    } else {
      ov.v = qv.v;   // V: pass bf16 bits through unchanged
    }
    *(bf16x8*)(&Ts[r][cg]) = ov.v;
  }
  __syncthreads();
  int wv = t >> 6, lane = t & 63;
  bf16* base = KM ? KT : VTo;
  int nloc = (lane & 7) * 8;
  int gsub = lane >> 3;
#pragma unroll
  for (int k = 0; k < 8; ++k) {
    int c = wv * 64 + k * 8 + gsub;
    union { bf16x8 v; bf16 e[8]; } pk;
#pragma unroll
    for (int i = 0; i < 8; ++i) pk.e[i] = Ts[nloc + i][c];
    *(bf16x8*)(base + ((size_t)(b * CC + c)) * NN + n0 + nloc) = pk.v;
    if (KM) {
      float s = 0.f;
#pragma unroll
      for (int i = 0; i < 8; ++i) s += b2f(pk.e[i]);
      s += __shfl_xor(s, 1);
      s += __shfl_xor(s, 2);
      s += __shfl_xor(s, 4);
      if ((lane & 7) == 0) atomicAdd(&ksum[b * CC + c], s);
    }
  }
}

// ---------- kvTb[b][d][c] = bf16(sum_ks kvpartB[b*16+ks][d][c]) (bf16 partials) ----------
__global__ __launch_bounds__(256) void kvred_kern(const bf16* __restrict__ part,
                                                  bf16* __restrict__ kvTb) {
  int d = blockIdx.x, b = blockIdx.y, c = threadIdx.x;
  float s = 0.f;
#pragma unroll
  for (int ks = 0; ks < 16; ++ks)
    s += b2f(part[((size_t)(b * 16 + ks) * CC + d) * CC + c]);
  kvTb[((size_t)b * CC + d) * CC + c] = f2b(s);
}

// ---------- rden: 1 row per wave, 4 rows per block ----------
__global__ __launch_bounds__(256) void den_kern(const bf16* __restrict__ PQ,
                                                const float* __restrict__ ksum,
                                                float* __restrict__ rden) {
  int b = blockIdx.y;
  int n = blockIdx.x * 4 + (threadIdx.x >> 6);
  int lane = threadIdx.x & 63;
  size_t m = (size_t)b * NN + n;
  union { bf16x4 v; bf16 e[4]; } u;
  u.v = *(const bf16x4*)(PQ + m * CC + lane * 4);
  const float* ks = ksum + b * CC + lane * 4;
  float s = 0.f;
#pragma unroll
  for (int j = 0; j < 4; ++j) s += b2f(u.e[j]) * ks[j];
#pragma unroll
  for (int off = 32; off >= 1; off >>= 1) s += __shfl_down(s, off);
  if (lane == 0) rden[m] = 1.f / (s + 1e-5f);
}

// ---------- DyT stats pass: per-row (mu, rs) + pool partial; no T write ----------
__global__ __launch_bounds__(256) void dytstat_kern(const float* __restrict__ X,
                                                    const float* __restrict__ g,
                                                    const float* __restrict__ bt,
                                                    float2* __restrict__ stats,
                                                    float* __restrict__ poolq) {
  int wv = threadIdx.x >> 6;
  int m = blockIdx.x * 4 + wv;
  int lane = threadIdx.x & 63;
  size_t base = (size_t)m * CC + lane * 4;
  f32x4v x = *(const f32x4v*)(X + base);
  float s = (x[0] + x[1]) + (x[2] + x[3]);
  float q = fmaf(x[0], x[0], fmaf(x[1], x[1], fmaf(x[2], x[2], x[3] * x[3])));
#pragma unroll
  for (int off = 32; off >= 1; off >>= 1) {
    s += __shfl_xor(s, off);
    q += __shfl_xor(q, off);
  }
  float mu = s * (1.f / 256.f);
  float var = (q - 256.f * mu * mu) * (1.f / 255.f);
  float sd = sqrtf(fmaxf(var, 0.f)) + 1e-5f;
  float rs = frcp(sd);
  if (lane == 0) stats[m] = make_float2(mu, rs);
  f32x4v gv = *(const f32x4v*)(g + lane * 4);
  f32x4v bv = *(const f32x4v*)(bt + lane * 4);
  f32x4v o;
#pragma unroll
  for (int j = 0; j < 4; ++j)
    o[j] = tanhfast(fmaf(gv[j] * (x[j] - mu), rs, bv[j]));
  __shared__ float ps[4][260];
#pragma unroll
  for (int j = 0; j < 4; ++j) ps[wv][lane * 4 + j] = o[j];
  __syncthreads();
  if (wv == 0) {
    f32x4v pv;
#pragma unroll
    for (int j = 0; j < 4; ++j) {
      int c = lane * 4 + j;
      pv[j] = (ps[0][c] + ps[1][c]) + (ps[2][c] + ps[3][c]);
    }
    *(f32x4v*)(poolq + (size_t)blockIdx.x * 256 + lane * 4) = pv;
  }
}

// ---------- poolred: pool16[(b*16+s)][c] = sum of 64 block-partials ----------
__global__ __launch_bounds__(256) void poolred_kern(const float* __restrict__ poolq,
                                                    float* __restrict__ pool16) {
  int s = blockIdx.x, b = blockIdx.y, c = threadIdx.x;
  float acc = 0.f;
#pragma unroll 8
  for (int k = 0; k < 64; ++k)
    acc += poolq[((size_t)(b * 1024 + s * 64 + k)) * 256 + c];
  pool16[(size_t)(b * 16 + s) * 256 + c] = acc;
}

// ---------- gate[b][o] = sigmoid(m_w . pool[b]/4096 + m_b) ----------
__global__ __launch_bounds__(256) void gate_kern(const float* __restrict__ pool16,
                                                 const float* __restrict__ w,
                                                 const float* __restrict__ bias,
                                                 float* __restrict__ gate) {
  int b = blockIdx.x, o = threadIdx.x;
  __shared__ float p[CC];
  float s = 0.f;
#pragma unroll
  for (int k = 0; k < 16; ++k) s += pool16[(size_t)(b * 16 + k) * 256 + o];
  p[o] = s * (1.f / 4096.f);
  __syncthreads();
  float acc = bias[o];
  for (int c = 0; c < CC; ++c) acc += p[c] * w[o * CC + c];
  gate[b * CC + o] = sigmf(acc);
}

// ---------- U1b = bf16(dyt(A,stats1)*gate1) (bit-identical to stored-T1 path) ----------
__global__ __launch_bounds__(256) void scale_from_A(const float* __restrict__ X,
                                                    const float2* __restrict__ stats,
                                                    const float* __restrict__ gate,
                                                    const float* __restrict__ g,
                                                    const float* __restrict__ bt,
                                                    bf16* __restrict__ Ob) {
  int wv = threadIdx.x >> 6;
  int m = blockIdx.x * 4 + wv;
  int lane = threadIdx.x & 63;
  int b = m >> 12;
  size_t base = (size_t)m * CC + lane * 4;
  f32x4v x = *(const f32x4v*)(X + base);
  float2 st = stats[m];
  f32x4v gv = *(const f32x4v*)(g + lane * 4);
  f32x4v bv = *(const f32x4v*)(bt + lane * 4);
  f32x4v gg = *(const f32x4v*)(gate + b * CC + lane * 4);
  union { bf16x4 v; bf16 e[4]; } ob;
#pragma unroll
  for (int j = 0; j < 4; ++j) {
    float tv = tanhfast(fmaf(gv[j] * (x[j] - st.x), st.y, bv[j]));
    ob.e[j] = f2b(tv * gg[j]);
  }
  *(bf16x4*)(Ob + base) = ob.v;
}

// ---------- depthwise 3x3 sliding-window helper (bf16 input, stride templated) ----------
template <int STRIDE>
__device__ __forceinline__ void dw_loadrow_b16(float (&row)[3][4], const bf16* __restrict__ Xb,
                                               int yy, int x, int dl, int dr) {
  if (yy < 0 || yy >= HW) {
#pragma unroll
    for (int cx = 0; cx < 3; ++cx)
#pragma unroll
      for (int j = 0; j < 4; ++j) row[cx][j] = 0.f;
    return;
  }
  const bf16* base = Xb + ((size_t)yy * HW + x) * (size_t)STRIDE;
  union U { bf16x4 v; bf16 e[4]; } um, ul, ur;
  um.v = *(const bf16x4*)base;
  ul.v = *(const bf16x4*)(base + dl);
  ur.v = *(const bf16x4*)(base + dr);
#pragma unroll
  for (int j = 0; j < 4; ++j) {
    row[0][j] = b2f(ul.e[j]);
    row[1][j] = b2f(um.e[j]);
    row[2][j] = b2f(ur.e[j]);
  }
}

// ---------- depthwise 3x3 + sigmoid, bf16 in (Hb) -> bf16 out (psi), 2-row load-ahead ----------
__global__ __launch_bounds__(256) void dwconv_psi_v2(const bf16* __restrict__ X,
                                                     const float* __restrict__ w,
                                                     const float* __restrict__ bias,
                                                     bf16* __restrict__ Y) {
  int i = blockIdx.x;
  int lin = (i & 7) * 64 + (i >> 3);
  int xg = lin & 15, yc = (lin >> 4) & 3, b = lin >> 6;
  int c0 = (threadIdx.x & 63) * 4;
  int x  = xg * 4 + (threadIdx.x >> 6);
  int y0 = yc * 16;
  const bf16* Xb = X + (size_t)b * NN * CC + c0;
  bf16* Yb      = Y + (size_t)b * NN * CC + c0;
  float wt[9][4], bs[4];
#pragma unroll
  for (int j = 0; j < 4; ++j) {
    bs[j] = bias[c0 + j];
#pragma unroll
    for (int t9 = 0; t9 < 9; ++t9) wt[t9][j] = w[(c0 + j) * 9 + t9];
  }
  const bool xl = (x > 0), xr = (x < HW - 1);
  if (!xl) {
#pragma unroll
    for (int j = 0; j < 4; ++j) wt[0][j] = wt[3][j] = wt[6][j] = 0.f;
  }
  if (!xr) {
#pragma unroll
    for (int j = 0; j < 4; ++j) wt[2][j] = wt[5][j] = wt[8][j] = 0.f;
  }
  const int dl = xl ? -CC : 0, dr = xr ? CC : 0;
  float win[5][3][4];
  dw_loadrow_b16<CC>(win[0], Xb, y0 - 1, x, dl, dr);
  dw_loadrow_b16<CC>(win[1], Xb, y0,     x, dl, dr);
  dw_loadrow_b16<CC>(win[2], Xb, y0 + 1, x, dl, dr);
  dw_loadrow_b16<CC>(win[3], Xb, y0 + 2, x, dl, dr);
#pragma unroll
  for (int ii = 0; ii < 16; ++ii) {
    dw_loadrow_b16<CC>(win[(ii + 4) % 5], Xb, y0 + ii + 3, x, dl, dr);
    const int rt = ii % 5, rm = (ii + 1) % 5, rb = (ii + 2) % 5;
    union { bf16x4 v; bf16 e[4]; } o;
#pragma unroll
    for (int j = 0; j < 4; ++j) {
      float a = bs[j];
#pragma unroll
      for (int cx = 0; cx < 3; ++cx) {
        a = fmaf(win[rt][cx][j], wt[cx][j], a);
        a = fmaf(win[rm][cx][j], wt[3 + cx][j], a);
        a = fmaf(win[rb][cx][j], wt[6 + cx][j], a);
      }
      o.e[j] = f2b(sigmf(a));
    }
    *(bf16x4*)(Yb + ((size_t)(y0 + ii) * HW + x) * (size_t)CC) = o.v;
  }
}

// ---------- depthwise 3x3 + gelu, bf16 in/out (1024ch), 2-row load-ahead ----------
__global__ __launch_bounds__(256) void dwconv1024_v2(const bf16* __restrict__ X,
                                                     const float* __restrict__ w,
                                                     const float* __restrict__ bias,
                                                     bf16* __restrict__ Y) {
  int i = blockIdx.x;
  int lin = (i & 7) * 256 + (i >> 3);
  int x = lin & 63, yc = (lin >> 6) & 3, b = lin >> 8;
  int c0 = threadIdx.x * 4;
  int y0 = yc * 16;
  const bf16* Xb = X + (size_t)b * NN * DH + c0;
  bf16* Yb       = Y + (size_t)b * NN * DH + c0;
  float wt[9][4], bs[4];
#pragma unroll
  for (int j = 0; j < 4; ++j) {
    bs[j] = bias[c0 + j];
#pragma unroll
    for (int t9 = 0; t9 < 9; ++t9) wt[t9][j] = w[(c0 + j) * 9 + t9];
  }
  const bool xl = (x > 0), xr = (x < HW - 1);
  if (!xl) {
#pragma unroll
    for (int j = 0; j < 4; ++j) wt[0][j] = wt[3][j] = wt[6][j] = 0.f;
  }
  if (!xr) {
#pragma unroll
    for (int j = 0; j < 4; ++j) wt[2][j] = wt[5][j] = wt[8][j] = 0.f;
  }
  const int dl = xl ? -DH : 0, dr = xr ? DH : 0;
  float win[5][3][4];
  dw_loadrow_b16<DH>(win[0], Xb, y0 - 1, x, dl, dr);
  dw_loadrow_b16<DH>(win[1], Xb, y0,     x, dl, dr);
  dw_loadrow_b16<DH>(win[2], Xb, y0 + 1, x, dl, dr);
  dw_loadrow_b16<DH>(win[3], Xb, y0 + 2, x, dl, dr);
#pragma unroll
  for (int ii = 0; ii < 16; ++ii) {
    dw_loadrow_b16<DH>(win[(ii + 4) % 5], Xb, y0 + ii + 3, x, dl, dr);
    const int rt = ii % 5, rm = (ii + 1) % 5, rb = (ii + 2) % 5;
    union { bf16x4 v; bf16 e[4]; } o;
#pragma unroll
    for (int j = 0; j < 4; ++j) {
      float a = bs[j];
#pragma unroll
      for (int cx = 0; cx < 3; ++cx) {
        a = fmaf(win[rt][cx][j], wt[cx][j], a);
        a = fmaf(win[rm][cx][j], wt[3 + cx][j], a);
        a = fmaf(win[rb][cx][j], wt[6 + cx][j], a);
      }
      o.e[j] = f2b(geluf(a));
    }
    *(bf16x4*)(Yb + ((size_t)(y0 + ii) * HW + x) * (size_t)DH) = o.v;
  }
}

extern "C" void kernel_launch(void* const* d_in, const int* in_sizes, int n_in,
                              void* d_out, int out_size, void* d_ws, size_t ws_size,
                              hipStream_t stream) {
  (void)in_sizes; (void)n_in; (void)out_size; (void)ws_size;
  const float* x       = (const float*)d_in[0];
  const float* in_proj = (const float*)d_in[1];
  const float* wq_w = (const float*)d_in[2];   const float* wq_b = (const float*)d_in[3];
  const float* wk_w = (const float*)d_in[4];   const float* wk_b = (const float*)d_in[5];
  const float* wv_w = (const float*)d_in[6];   const float* wv_b = (const float*)d_in[7];
  const float* wo_w = (const float*)d_in[8];   const float* wo_b = (const float*)d_in[9];
  const float* psi_w = (const float*)d_in[10]; const float* psi_b = (const float*)d_in[11];
  const float* dyt_g = (const float*)d_in[12]; const float* dyt_b = (const float*)d_in[13];
  const float* m1_w = (const float*)d_in[14];  const float* m1_b = (const float*)d_in[15];
  const float* m2_w = (const float*)d_in[16];  const float* m2_b = (const float*)d_in[17];
  const float* we_w = (const float*)d_in[18];  const float* we_b = (const float*)d_in[19];
  const float* dw_w = (const float*)d_in[20];  const float* dw_b = (const float*)d_in[21];
  const float* wp_w = (const float*)d_in[22];  const float* wp_b = (const float*)d_in[23];
  const float* wout = (const float*)d_in[24];
  float* out = (float*)d_out;

  char* ws = (char*)d_ws;
  const size_t MB = 1u << 20;
  // f32 activations
  float* A     = (float*)(ws + 32 * MB);     // 32-64  : a+h -> U2 (alive to the end)
  // attention-phase buffers (dead before EDFFN)
  bf16*  psiB  = (bf16*)(ws + 64 * MB);      // 64-80
  bf16*  numb  = (bf16*)(ws + 80 * MB);      // 80-96
  bf16*  phiQ  = (bf16*)(ws + 96 * MB);      // 96-112
  bf16*  Hb    = (bf16*)(ws + 112 * MB);     // 112-128 (dead after wo GEMM, before e1)
  bf16*  phiKT = (bf16*)(ws + 128 * MB);     // 128-144 [B][C][N]
  bf16*  VT    = (bf16*)(ws + 144 * MB);     // 144-160 [B][C][N]
  bf16*  QKVr  = (bf16*)(ws + 160 * MB);     // 160-208 [MM][768] (48MB, dead before kv GEMM)
  bf16*  kvpartB = (bf16*)(ws + 160 * MB);   // 160-176 [128][C][C] bf16 (after qkmath)
  // EDFFN overlays
  bf16*  e1    = (bf16*)(ws + 64 * MB);      // 64-128 (64MB; attention bf16 bufs dead)
  bf16*  e2    = (bf16*)(ws + 128 * MB);     // 128-192 (64MB)
  bf16*  U1b   = (bf16*)(ws + 192 * MB);     // 192-208 (QKVr dead by scale_from_A)
  // bf16 weights (persistent) 208-210
  bf16* wqkvb = (bf16*)(ws + 208 * MB);      // 384KB [768][256]
  bf16* wob   = wqkvb + 196608;              // 128KB
  bf16* web   = wob + 65536;                 // 512KB [1024][256]
  bf16* wpb   = web + 262144;                // 512KB [256][1024]
  float* bqkv = (float*)(wpb + 262144);      // 3KB
  float* pose = (float*)(ws + 210 * MB);     // 210-214
  char*  small = ws + 214 * MB;
  float* ksum  = (float*)(small);                 // 8KB
  float* rden  = (float*)(small + 64 * 1024);     // 128KB
  float* pool16 = (float*)(small + 192 * 1024);   // 128KB [8][16][256]
  float* gate1 = (float*)(small + 704 * 1024);
  float* gate2 = (float*)(small + 720 * 1024);
  bf16*  kvTb  = (bf16*)(small + 768 * 1024);     // 1MB [8][C][C]
  float* poolq = (float*)(ws + 216 * MB);         // 216-224 [8192][256] block partials
  float2* stats1 = (float2*)(ws + 224 * MB);      // 256KB [MM] (mu, rs)
  float2* stats2 = (float2*)(ws + 225 * MB);      // 256KB [MM]

  dim3 blk(256);

  pos_kern<<<dim3(NN), blk, 0, stream>>>(pose);
  cvt_weights<<<dim3(1024, 6), blk, 0, stream>>>(wq_w, wk_w, wv_w, wo_w, we_w, wp_w,
                                                 wq_b, wk_b, wv_b,
                                                 wqkvb, wob, web, wpb, bqkv, ksum);
  inproj_tile<<<dim3(64, 4, BB), blk, 0, stream>>>(x, in_proj, Hb);

  // ---- attention ----
  dwconv_psi_v2<<<dim3(512), blk, 0, stream>>>(Hb, psi_w, psi_b, psiB);
  gemm_bf16<EPI_BIAS, false, false, true, bf16, float>
      <<<dim3(256, 6), blk, 0, stream>>>(Hb, wqkvb, bqkv, QKVr, CC, 768, nullptr, nullptr);
  qkmath_kern<<<dim3(MM / 64, 3), blk, 0, stream>>>(QKVr, pose, psiB, phiQ, phiKT, VT, ksum);
  gemm_bf16<EPI_PLAIN, false, true, false, bf16, float>
      <<<dim3(2, 2, 128), blk, 0, stream>>>(VT, phiKT, nullptr, kvpartB, NN, CC, nullptr, nullptr);
  kvred_kern<<<dim3(CC, BB), blk, 0, stream>>>(kvpartB, kvTb);
  den_kern<<<dim3(1024, BB), blk, 0, stream>>>(phiQ, ksum, rden);
  gemm_bf16<EPI_NUM, true, false, true, bf16, float>
      <<<dim3(256, 2), blk, 0, stream>>>(phiQ, kvTb, nullptr, numb, CC, CC, rden, nullptr);
  // wo GEMM with fused h-residual from Hb (bf16): A = wo_out + bias + Hb   (last read of Hb)
  gemm_bf16<EPI_ADD1, false, false, true, float, bf16>
      <<<dim3(256, 2), blk, 0, stream>>>(numb, wob, wo_b, A, CC, CC, nullptr, Hb);

  // ---- U1 = mona1(dyt(A)); stats-only DyT, U1b recomputed from A ----
  dytstat_kern<<<dim3(MM / 4), blk, 0, stream>>>(A, dyt_g, dyt_b, stats1, poolq);
  poolred_kern<<<dim3(16, BB), blk, 0, stream>>>(poolq, pool16);
  gate_kern<<<dim3(BB), blk, 0, stream>>>(pool16, m1_w, m1_b, gate1);
  scale_from_A<<<dim3(MM / 4), blk, 0, stream>>>(A, stats1, gate1, dyt_g, dyt_b, U1b);

  // ---- EDFFN, single pass over all 8 batches; U1b residual fused into wp ----
  gemm_bf16<EPI_BIAS, false, false, true, bf16, float>
      <<<dim3(256, 8), blk, 0, stream>>>(U1b, web, we_b, e1, CC, DH, nullptr, nullptr);
  dwconv1024_v2<<<dim3(2048), blk, 0, stream>>>(e1, dw_w, dw_b, e2);
  gemm_bf16<EPI_RESID, false, false, true, float, bf16>
      <<<dim3(256, 2), blk, 0, stream>>>(e2, wpb, wp_b, A, DH, CC, nullptr, U1b);

  // ---- Y = mona2(dyt(U2)); stats-only DyT, dyt recomputed in out_proj staging ----
  dytstat_kern<<<dim3(MM / 4), blk, 0, stream>>>(A, dyt_g, dyt_b, stats2, poolq);
  poolred_kern<<<dim3(16, BB), blk, 0, stream>>>(poolq, pool16);
  gate_kern<<<dim3(BB), blk, 0, stream>>>(pool16, m2_w, m2_b, gate2);

  // ---- out_proj + SiLU, transposed write; dyt(A)*gate2 applied during staging ----
  outproj_tile<<<dim3(64, 1, BB), blk, 0, stream>>>(A, stats2, gate2, dyt_g, dyt_b, wout, out);
}